// Round 1
// baseline (1364.605 us; speedup 1.0000x reference)
//
#include <hip/hip_runtime.h>
#include <stdint.h>

typedef __attribute__((ext_vector_type(8))) __bf16 bf16x8;
typedef __attribute__((ext_vector_type(4))) float f32x4;
typedef unsigned short u16;

#define DEV static __device__ __forceinline__

constexpr int NB = 8;           // batch
constexpr int AA = 2784;        // anchors
constexpr int AM1 = 2783;       // A-1
constexpr int DD = 1408;        // D = 64*22
constexpr int MT = NB * AA;     // 22272 total rows

DEV u16 f2bf(float f) {
  uint32_t u = __builtin_bit_cast(uint32_t, f);
  u += 0x7FFFu + ((u >> 16) & 1u);
  return (u16)(u >> 16);
}

// async global->LDS, 16B per lane. LDS dest is wave-uniform base + lane*16 by HW.
DEV void load16_lds(const void* g, void* l) {
  auto gp = (const __attribute__((address_space(1))) uint32_t*)(uintptr_t)g;
  auto lp = (__attribute__((address_space(3))) uint32_t*)(uint32_t)(uintptr_t)l;
  __builtin_amdgcn_global_load_lds(gp, lp, 16, 0, 0);
}

// ---------------- 1x1 conv: feats[b][o][h][w] ----------------
__global__ __launch_bounds__(256) void conv_k(const float* __restrict__ x,
                                              const float* __restrict__ w,
                                              const float* __restrict__ bias,
                                              float* __restrict__ feats) {
  __shared__ float xs[256 * 40];
  int bb = blockIdx.x / 22, h = blockIdx.x % 22;
  const float* xp = x + (size_t)bb * 256 * 880 + h * 40;
  for (int l = threadIdx.x; l < 256 * 40; l += 256)
    xs[l] = xp[(l / 40) * 880 + (l % 40)];
  __syncthreads();
  for (int l = threadIdx.x; l < 64 * 40; l += 256) {
    int o = l / 40, ww = l % 40;
    float acc = bias[o];
    const float* wr = w + o * 256;
#pragma unroll 8
    for (int c = 0; c < 256; ++c) acc += xs[c * 40 + ww] * wr[c];
    feats[((size_t)(bb * 64 + o) * 22 + h) * 40 + ww] = acc;
  }
}

// ---------------- gather + mask -> baf bf16 (B,A,D) ----------------
// invalid_mask is jnp.bool_; harness byte-width ambiguous (u8 vs i32): probe.
__global__ __launch_bounds__(128) void gather_k(const float* __restrict__ feats,
                                                const int* __restrict__ cut,
                                                const unsigned char* __restrict__ inv,
                                                u16* __restrict__ baf) {
  unsigned probe = 0;
#pragma unroll
  for (int t = 0; t < 10; ++t)
    probe |= (unsigned)inv[4 * t + 1] | (unsigned)inv[4 * t + 2] | (unsigned)inv[4 * t + 3];
  const bool is_u8 = (probe != 0);  // i32 storage -> high bytes all zero
  int ba = blockIdx.x;
  int b = ba / AA, a = ba - (ba / AA) * AA;
  for (int d = threadIdx.x; d < DD; d += 128) {
    int o = d / 22, h = d - o * 22;
    int msk = is_u8 ? (int)inv[a * 22 + h] : ((const int*)inv)[a * 22 + h];
    float v = 0.f;
    if (!msk) v = feats[((size_t)(b * 64 + o) * 22 + h) * 40 + cut[a * 22 + h]];
    baf[(size_t)ba * DD + d] = f2bf(v);
  }
}

// ---------------- baf (B,A,D) -> baf_t (B,D,A), 64x64 LDS tiles ----------------
__global__ __launch_bounds__(256) void tr_baf_k(const u16* __restrict__ baf,
                                                u16* __restrict__ bft) {
  __shared__ u16 t[64][65];
  int a0 = blockIdx.x * 64, d0 = blockIdx.y * 64, b = blockIdx.z;
  int tx = threadIdx.x & 63, ty = threadIdx.x >> 6;
  for (int r = ty; r < 64; r += 4) {
    int a = a0 + r;
    t[r][tx] = (a < AA) ? baf[((size_t)b * AA + a) * DD + d0 + tx] : (u16)0;
  }
  __syncthreads();
  for (int r = ty; r < 64; r += 4) {
    int a = a0 + tx;
    if (a < AA) bft[((size_t)b * DD + d0 + r) * AA + a] = t[tx][r];
  }
}

// ---------------- attn_w (1408,2783) f32 -> attw_t (2816,1408) bf16, zero pad ----------------
__global__ __launch_bounds__(256) void tr_attw_k(const float* __restrict__ w,
                                                 u16* __restrict__ wt) {
  __shared__ u16 t[64][65];
  int n0 = blockIdx.x * 64, k0 = blockIdx.y * 64;
  int tx = threadIdx.x & 63, ty = threadIdx.x >> 6;
  for (int r = ty; r < 64; r += 4) {
    int n = n0 + tx;
    t[r][tx] = (n < AM1) ? f2bf(w[(size_t)(k0 + r) * AM1 + n]) : (u16)0;
  }
  __syncthreads();
  for (int r = ty; r < 64; r += 4)
    wt[(size_t)(n0 + r) * 1408 + k0 + tx] = t[tx][r];
}

// ---------------- pack head weights: wt[n][k], n<2 cls, 2..145 reg, pad->160 ----------------
__global__ __launch_bounds__(256) void wt_k(const float* __restrict__ cw,
                                            const float* __restrict__ rw,
                                            u16* __restrict__ wt) {
  int n = blockIdx.x;
  for (int k = threadIdx.x; k < 2816; k += 256) {
    float v = 0.f;
    if (n < 2) v = cw[(size_t)k * 2 + n];
    else if (n < 146) v = rw[(size_t)k * 144 + (n - 2)];
    wt[(size_t)n * 2816 + k] = f2bf(v);
  }
}

// ---------------- props cols 2,3 = anchors[:,2:4] ----------------
__global__ __launch_bounds__(256) void anch_k(const float* __restrict__ anch,
                                              float* __restrict__ props) {
  int idx = blockIdx.x * 256 + threadIdx.x;
  if (idx >= MT) return;
  int a = idx % AA;
  props[(size_t)idx * 148 + 2] = anch[a * 148 + 2];
  props[(size_t)idx * 148 + 3] = anch[a * 148 + 3];
}

// ---------------- row softmax over 2784-wide rows, diag forced to 0 ----------------
__global__ __launch_bounds__(256) void softmax_k(float* __restrict__ attn) {
  const int row = blockIdx.x;
  const int i = row % AA;
  float* p = attn + (size_t)row * AA;
  const int tid = threadIdx.x;
  float v[11];
  float mx = -1e30f;
#pragma unroll
  for (int it = 0; it < 11; ++it) {
    int j = tid + it * 256;
    float xv = -1e30f;
    if (j < AA && j != i) xv = p[j];
    v[it] = xv;
    mx = fmaxf(mx, xv);
  }
#pragma unroll
  for (int o = 1; o < 64; o <<= 1) mx = fmaxf(mx, __shfl_xor(mx, o));
  __shared__ float rm[4], rs[4];
  if (!(tid & 63)) rm[tid >> 6] = mx;
  __syncthreads();
  mx = fmaxf(fmaxf(rm[0], rm[1]), fmaxf(rm[2], rm[3]));
  float s = 0.f;
  float e[11];
#pragma unroll
  for (int it = 0; it < 11; ++it) {
    float xv = v[it];
    float ev = (xv > -1e29f) ? __expf(xv - mx) : 0.f;
    e[it] = ev;
    s += ev;
  }
#pragma unroll
  for (int o = 1; o < 64; o <<= 1) s += __shfl_xor(s, o);
  if (!(tid & 63)) rs[tid >> 6] = s;
  __syncthreads();
  s = (rs[0] + rs[1]) + (rs[2] + rs[3]);
  float inv = 1.f / s;
#pragma unroll
  for (int it = 0; it < 11; ++it) {
    int j = tid + it * 256;
    if (j < AA) p[j] = (j == i) ? 0.f : e[it] * inv;
  }
}

// ---------------- MFMA GEMM, B^T form: C[m][n] = sum_k A[m][k]*Bt[n][k] ----------------
// MODE 1: scores -> scattered into attn_mat (+bias). A=baf, Bt=attw_t, K=1408.
// MODE 2: att_feat. A=attention f32 (reg-staged ->bf16), Bt=baf_t[b], K=2784.
// MODE 3: head. A=[att_feat|baf] (K=2816), Bt=wt (160 rows), fused bias/sigmoid/anchor.
template <int MODE, int BN>
__global__ __launch_bounds__(256) void gemm_k(const u16* __restrict__ Aa,
                                              const u16* __restrict__ Aa2,
                                              const float* __restrict__ Af,
                                              const u16* __restrict__ Bt,
                                              float* __restrict__ outf,
                                              u16* __restrict__ outh,
                                              const float* __restrict__ b1,
                                              const float* __restrict__ b2,
                                              const float* __restrict__ anch) {
  constexpr int K = (MODE == 1) ? 1408 : (MODE == 2) ? 2784 : 2816;
  constexpr int HN = BN / 2;
  constexpr int NF = BN / 32;
  __shared__ __align__(16) u16 As[128 * 32];
  __shared__ __align__(16) u16 Bs[BN * 32];
  const int tid = threadIdx.x;
  const int lane = tid & 63;
  const int wm = tid >> 7, wn = (tid >> 6) & 1;
  const int m0 = blockIdx.x * 128;
  const int n0 = blockIdx.y * BN;
  const int bz = blockIdx.z;
  const int l16 = lane & 15, lq = lane >> 4;

  f32x4 acc[4][NF];
#pragma unroll
  for (int i = 0; i < 4; ++i)
#pragma unroll
    for (int j = 0; j < NF; ++j) acc[i][j] = 0.f;

  for (int k0 = 0; k0 < K; k0 += 32) {
    __syncthreads();
    // ---- stage A tile (128 x 32 bf16) ----
    if constexpr (MODE == 2) {
      const float* Ab = Af + (size_t)bz * AA * AA;
#pragma unroll
      for (int inst = 0; inst < 4; ++inst) {
        int c = tid + inst * 256;       // 1024 chunks of 4 floats
        int r = c >> 3, c4 = (c & 7) * 4;
        int sr = m0 + r; sr = sr < AM1 ? sr : AM1;   // clamp tile overhang
        const float4 v = *(const float4*)(Ab + (size_t)sr * AA + k0 + c4);
        ushort4 hh;
        hh.x = f2bf(v.x); hh.y = f2bf(v.y); hh.z = f2bf(v.z); hh.w = f2bf(v.w);
        *(ushort4*)&As[r * 32 + c4] = hh;
      }
    } else {
      const u16* Ab; int kk;
      if constexpr (MODE == 3) {
        Ab = (k0 < 1408) ? Aa : Aa2;
        kk = (k0 < 1408) ? k0 : k0 - 1408;
      } else { Ab = Aa; kk = k0; }
#pragma unroll
      for (int inst = 0; inst < 2; ++inst) {
        int c = tid + inst * 256;       // 512 chunks of 8 bf16
        load16_lds(Ab + (size_t)(m0 + (c >> 2)) * 1408 + kk + (c & 3) * 8, &As[c * 8]);
      }
    }
    // ---- stage B tile (BN x 32 bf16) ----
    {
      constexpr int RL = (MODE == 1) ? 1408 : (MODE == 2) ? 2784 : 2816;
      const u16* Bb = (MODE == 2) ? Bt + (size_t)bz * 1408 * 2784 : Bt;
      constexpr int NCH = BN * 4;
      for (int c = tid; c < NCH; c += 256)
        load16_lds(Bb + (size_t)(n0 + (c >> 2)) * RL + k0 + (c & 3) * 8, &Bs[c * 8]);
    }
    __syncthreads();
    // ---- 16/20 MFMAs ----
    bf16x8 av[4], bv[NF];
#pragma unroll
    for (int mt = 0; mt < 4; ++mt)
      av[mt] = *(const bf16x8*)&As[(wm * 64 + mt * 16 + l16) * 32 + lq * 8];
#pragma unroll
    for (int nt = 0; nt < NF; ++nt)
      bv[nt] = *(const bf16x8*)&Bs[(wn * HN + nt * 16 + l16) * 32 + lq * 8];
#pragma unroll
    for (int mt = 0; mt < 4; ++mt)
#pragma unroll
      for (int nt = 0; nt < NF; ++nt)
        acc[mt][nt] = __builtin_amdgcn_mfma_f32_16x16x32_bf16(av[mt], bv[nt], acc[mt][nt], 0, 0, 0);
  }

  // ---- epilogue ----  C/D map: col = lane&15, row = (lane>>4)*4 + reg
  if constexpr (MODE == 1) {
#pragma unroll
    for (int nt = 0; nt < NF; ++nt) {
      int n = n0 + wn * HN + nt * 16 + l16;
      if (n >= AM1) continue;
      float bb = b1[n];
#pragma unroll
      for (int mt = 0; mt < 4; ++mt)
#pragma unroll
        for (int r = 0; r < 4; ++r) {
          int m = m0 + wm * 64 + mt * 16 + lq * 4 + r;
          int ii = m % AA;
          int col = n + (n >= ii);   // scatter: skip diagonal
          outf[(size_t)m * AA + col] = acc[mt][nt][r] + bb;
        }
    }
  } else if constexpr (MODE == 2) {
#pragma unroll
    for (int mt = 0; mt < 4; ++mt)
#pragma unroll
      for (int r = 0; r < 4; ++r) {
        int m = m0 + wm * 64 + mt * 16 + lq * 4 + r;
        if (m >= AA) continue;
        size_t base = ((size_t)bz * AA + m) * DD;
#pragma unroll
        for (int nt = 0; nt < NF; ++nt) {
          int n = n0 + wn * HN + nt * 16 + l16;
          outh[base + n] = f2bf(acc[mt][nt][r]);
        }
      }
  } else {
#pragma unroll
    for (int nt = 0; nt < NF; ++nt) {
      int n = wn * HN + nt * 16 + l16;   // n0 == 0
      if (n >= 146) continue;
#pragma unroll
      for (int mt = 0; mt < 4; ++mt)
#pragma unroll
        for (int r = 0; r < 4; ++r) {
          int m = m0 + wm * 64 + mt * 16 + lq * 4 + r;
          int ii = m % AA;
          float v = acc[mt][nt][r];
          if (n < 2) {
            outf[(size_t)m * 148 + n] = v + b1[n];
          } else {
            int rr = n - 2;
            v += b2[rr];
            if (rr >= 72) v = 1.f / (1.f + __expf(-v));
            outf[(size_t)m * 148 + 4 + rr] = anch[ii * 148 + 4 + rr] + v;
          }
        }
    }
  }
}

extern "C" void kernel_launch(void* const* d_in, const int* in_sizes, int n_in,
                              void* d_out, int out_size, void* d_ws, size_t ws_size,
                              hipStream_t stream) {
  const float* x       = (const float*)d_in[0];
  const float* conv_w  = (const float*)d_in[1];
  const float* conv_b  = (const float*)d_in[2];
  const float* attn_w  = (const float*)d_in[3];
  const float* attn_b  = (const float*)d_in[4];
  const float* cls_w   = (const float*)d_in[5];
  const float* cls_b   = (const float*)d_in[6];
  const float* reg_w   = (const float*)d_in[7];
  const float* reg_b   = (const float*)d_in[8];
  const float* anchors = (const float*)d_in[9];
  const int*   cut_xs  = (const int*)d_in[10];
  const unsigned char* inv = (const unsigned char*)d_in[11];

  float* props = (float*)d_out;
  float* attn  = props + (size_t)MT * 148;   // attn_mat region of d_out

  // workspace carve-up (~190 MiB total)
  char* wp = (char*)d_ws;
  auto take = [&](size_t bytes) { char* p = wp; wp += (bytes + 255) & ~(size_t)255; return p; };
  float* feats = (float*)take((size_t)450560 * 4);           // 1.8 MB
  u16* baf    = (u16*)take((size_t)MT * DD * 2);             // 62.7 MB
  u16* baft   = (u16*)take((size_t)MT * DD * 2);             // 62.7 MB
  u16* attwt  = (u16*)take((size_t)2816 * 1408 * 2);         // 7.9 MB
  u16* attf   = (u16*)take((size_t)MT * DD * 2);             // 62.7 MB
  u16* wt     = (u16*)take((size_t)160 * 2816 * 2);          // 0.9 MB

  conv_k<<<dim3(176), 256, 0, stream>>>(x, conv_w, conv_b, feats);
  gather_k<<<dim3(MT), 128, 0, stream>>>(feats, cut_xs, inv, baf);
  tr_baf_k<<<dim3(44, 22, 8), 256, 0, stream>>>(baf, baft);
  tr_attw_k<<<dim3(44, 22), 256, 0, stream>>>(attn_w, attwt);
  wt_k<<<dim3(160), 256, 0, stream>>>(cls_w, reg_w, wt);
  anch_k<<<dim3(87), 256, 0, stream>>>(anchors, props);

  // GEMM1: scores scattered (+bias) straight into attn_mat region
  gemm_k<1, 128><<<dim3(174, 22), 256, 0, stream>>>(baf, nullptr, nullptr, attwt,
                                                    attn, nullptr, attn_b, nullptr, nullptr);
  // softmax in place (diag -> 0): finalizes attn_mat output
  softmax_k<<<dim3(MT), 256, 0, stream>>>(attn);
  // GEMM2: att_feat = attn @ baf  (A reg-staged f32->bf16, B = baf^T)
  gemm_k<2, 128><<<dim3(22, 11, 8), 256, 0, stream>>>(nullptr, nullptr, attn, baft,
                                                      nullptr, attf, nullptr, nullptr, nullptr);
  // GEMM3: head, fused bias + sigmoid + anchors into props
  gemm_k<3, 160><<<dim3(174, 1), 256, 0, stream>>>(attf, baf, nullptr, wt,
                                                   props, nullptr, cls_b, reg_b, anchors);
}

// Round 2
// 1018.846 us; speedup vs baseline: 1.3394x; 1.3394x over previous
//
#include <hip/hip_runtime.h>
#include <stdint.h>

typedef __attribute__((ext_vector_type(8))) __bf16 bf16x8;
typedef __attribute__((ext_vector_type(4))) float f32x4;
typedef unsigned short u16;

#define DEV static __device__ __forceinline__

constexpr int NB = 8;           // batch
constexpr int AA = 2784;        // anchors
constexpr int AM1 = 2783;       // A-1
constexpr int DD = 1408;        // D = 64*22
constexpr int MT = NB * AA;     // 22272 total rows
constexpr int MH = MT / 2;      // 11136 rows per half (4 batches)

DEV u16 f2bf(float f) {
  uint32_t u = __builtin_bit_cast(uint32_t, f);
  u += 0x7FFFu + ((u >> 16) & 1u);
  return (u16)(u >> 16);
}
DEV float bf2f(unsigned v) { return __builtin_bit_cast(float, v << 16); }

// async global->LDS, 16B per lane. LDS dest is wave-uniform base + lane*16 by HW.
DEV void load16_lds(const void* g, void* l) {
  auto gp = (const __attribute__((address_space(1))) uint32_t*)(uintptr_t)g;
  auto lp = (__attribute__((address_space(3))) uint32_t*)(uint32_t)(uintptr_t)l;
  __builtin_amdgcn_global_load_lds(gp, lp, 16, 0, 0);
}

// ---------------- 1x1 conv: feats[b][o][h][w] ----------------
__global__ __launch_bounds__(256) void conv_k(const float* __restrict__ x,
                                              const float* __restrict__ w,
                                              const float* __restrict__ bias,
                                              float* __restrict__ feats) {
  __shared__ float xs[256 * 40];
  int bb = blockIdx.x / 22, h = blockIdx.x % 22;
  const float* xp = x + (size_t)bb * 256 * 880 + h * 40;
  for (int l = threadIdx.x; l < 256 * 40; l += 256)
    xs[l] = xp[(l / 40) * 880 + (l % 40)];
  __syncthreads();
  for (int l = threadIdx.x; l < 64 * 40; l += 256) {
    int o = l / 40, ww = l % 40;
    float acc = bias[o];
    const float* wr = w + o * 256;
#pragma unroll 8
    for (int c = 0; c < 256; ++c) acc += xs[c * 40 + ww] * wr[c];
    feats[((size_t)(bb * 64 + o) * 22 + h) * 40 + ww] = acc;
  }
}

// ---------------- gather + mask -> baf bf16 (B,A,D) ----------------
__global__ __launch_bounds__(128) void gather_k(const float* __restrict__ feats,
                                                const int* __restrict__ cut,
                                                const unsigned char* __restrict__ inv,
                                                u16* __restrict__ baf) {
  unsigned probe = 0;
#pragma unroll
  for (int t = 0; t < 10; ++t)
    probe |= (unsigned)inv[4 * t + 1] | (unsigned)inv[4 * t + 2] | (unsigned)inv[4 * t + 3];
  const bool is_u8 = (probe != 0);  // i32 storage -> high bytes all zero
  int ba = blockIdx.x;
  int b = ba / AA, a = ba - (ba / AA) * AA;
  for (int d = threadIdx.x; d < DD; d += 128) {
    int o = d / 22, h = d - o * 22;
    int msk = is_u8 ? (int)inv[a * 22 + h] : ((const int*)inv)[a * 22 + h];
    float v = 0.f;
    if (!msk) v = feats[((size_t)(b * 64 + o) * 22 + h) * 40 + cut[a * 22 + h]];
    baf[(size_t)ba * DD + d] = f2bf(v);
  }
}

// ---------------- baf (B,A,D) -> baf_t (B,D,A) ----------------
__global__ __launch_bounds__(256) void tr_baf_k(const u16* __restrict__ baf,
                                                u16* __restrict__ bft) {
  __shared__ u16 t[64][65];
  int a0 = blockIdx.x * 64, d0 = blockIdx.y * 64, b = blockIdx.z;
  int tx = threadIdx.x & 63, ty = threadIdx.x >> 6;
  for (int r = ty; r < 64; r += 4) {
    int a = a0 + r;
    t[r][tx] = (a < AA) ? baf[((size_t)b * AA + a) * DD + d0 + tx] : (u16)0;
  }
  __syncthreads();
  for (int r = ty; r < 64; r += 4) {
    int a = a0 + tx;
    if (a < AA) bft[((size_t)b * DD + d0 + r) * AA + a] = t[tx][r];
  }
}

// ---------------- attn_w (1408,2783) f32 -> attw_t (2816,1408) bf16, zero pad ----------------
__global__ __launch_bounds__(256) void tr_attw_k(const float* __restrict__ w,
                                                 u16* __restrict__ wt) {
  __shared__ u16 t[64][65];
  int n0 = blockIdx.x * 64, k0 = blockIdx.y * 64;
  int tx = threadIdx.x & 63, ty = threadIdx.x >> 6;
  for (int r = ty; r < 64; r += 4) {
    int n = n0 + tx;
    t[r][tx] = (n < AM1) ? f2bf(w[(size_t)(k0 + r) * AM1 + n]) : (u16)0;
  }
  __syncthreads();
  for (int r = ty; r < 64; r += 4)
    wt[(size_t)(n0 + r) * 1408 + k0 + tx] = t[tx][r];
}

// ---------------- pack head weights: wt[n][k], n<2 cls, 2..145 reg, pad->160 ----------------
__global__ __launch_bounds__(256) void wt_k(const float* __restrict__ cw,
                                            const float* __restrict__ rw,
                                            u16* __restrict__ wt) {
  int n = blockIdx.x;
  for (int k = threadIdx.x; k < 2816; k += 256) {
    float v = 0.f;
    if (n < 2) v = cw[(size_t)k * 2 + n];
    else if (n < 146) v = rw[(size_t)k * 144 + (n - 2)];
    wt[(size_t)n * 2816 + k] = f2bf(v);
  }
}

// ---------------- props cols 2,3 = anchors[:,2:4] ----------------
__global__ __launch_bounds__(256) void anch_k(const float* __restrict__ anch,
                                              float* __restrict__ props) {
  int idx = blockIdx.x * 256 + threadIdx.x;
  if (idx >= MT) return;
  int a = idx % AA;
  props[(size_t)idx * 148 + 2] = anch[a * 148 + 2];
  props[(size_t)idx * 148 + 3] = anch[a * 148 + 3];
}

// ---------------- in-place row softmax on scattered bf16 attP rows ----------------
// attP[row][col], col==i excluded; writes normalized bf16 back, diag=0.
__global__ __launch_bounds__(256) void softmax_k(u16* __restrict__ attP) {
  const int row = blockIdx.x;            // 0..MH-1
  const int i = row % AA;
  u16* p = attP + (size_t)row * AA;
  const int tid = threadIdx.x;
  const int c0 = tid, c1 = tid + 256;    // 348 chunks of 8
  const bool has1 = (c1 < 348);
  uint4 h0 = ((const uint4*)p)[c0];
  uint4 h1 = has1 ? ((const uint4*)p)[c1] : make_uint4(0, 0, 0, 0);
  float v0[8], v1[8];
  v0[0] = bf2f(h0.x & 0xffffu); v0[1] = bf2f(h0.x >> 16);
  v0[2] = bf2f(h0.y & 0xffffu); v0[3] = bf2f(h0.y >> 16);
  v0[4] = bf2f(h0.z & 0xffffu); v0[5] = bf2f(h0.z >> 16);
  v0[6] = bf2f(h0.w & 0xffffu); v0[7] = bf2f(h0.w >> 16);
  v1[0] = bf2f(h1.x & 0xffffu); v1[1] = bf2f(h1.x >> 16);
  v1[2] = bf2f(h1.y & 0xffffu); v1[3] = bf2f(h1.y >> 16);
  v1[4] = bf2f(h1.z & 0xffffu); v1[5] = bf2f(h1.z >> 16);
  v1[6] = bf2f(h1.w & 0xffffu); v1[7] = bf2f(h1.w >> 16);
  float mx = -3e38f;
#pragma unroll
  for (int e = 0; e < 8; ++e) if (c0 * 8 + e != i) mx = fmaxf(mx, v0[e]);
#pragma unroll
  for (int e = 0; e < 8; ++e) if (has1 && c1 * 8 + e != i) mx = fmaxf(mx, v1[e]);
#pragma unroll
  for (int o = 1; o < 64; o <<= 1) mx = fmaxf(mx, __shfl_xor(mx, o));
  __shared__ float rm[4], rs[4];
  if (!(tid & 63)) rm[tid >> 6] = mx;
  __syncthreads();
  mx = fmaxf(fmaxf(rm[0], rm[1]), fmaxf(rm[2], rm[3]));
  float s = 0.f, e0[8], e1[8];
#pragma unroll
  for (int e = 0; e < 8; ++e) {
    float t = (c0 * 8 + e != i) ? __expf(v0[e] - mx) : 0.f;
    e0[e] = t; s += t;
  }
#pragma unroll
  for (int e = 0; e < 8; ++e) {
    float t = (has1 && c1 * 8 + e != i) ? __expf(v1[e] - mx) : 0.f;
    e1[e] = t; s += t;
  }
#pragma unroll
  for (int o = 1; o < 64; o <<= 1) s += __shfl_xor(s, o);
  if (!(tid & 63)) rs[tid >> 6] = s;
  __syncthreads();
  s = (rs[0] + rs[1]) + (rs[2] + rs[3]);
  const float inv = 1.f / s;
  uint4 o0, o1;
  o0.x = (unsigned)f2bf(e0[0] * inv) | ((unsigned)f2bf(e0[1] * inv) << 16);
  o0.y = (unsigned)f2bf(e0[2] * inv) | ((unsigned)f2bf(e0[3] * inv) << 16);
  o0.z = (unsigned)f2bf(e0[4] * inv) | ((unsigned)f2bf(e0[5] * inv) << 16);
  o0.w = (unsigned)f2bf(e0[6] * inv) | ((unsigned)f2bf(e0[7] * inv) << 16);
  ((uint4*)p)[c0] = o0;
  if (has1) {
    o1.x = (unsigned)f2bf(e1[0] * inv) | ((unsigned)f2bf(e1[1] * inv) << 16);
    o1.y = (unsigned)f2bf(e1[2] * inv) | ((unsigned)f2bf(e1[3] * inv) << 16);
    o1.z = (unsigned)f2bf(e1[4] * inv) | ((unsigned)f2bf(e1[5] * inv) << 16);
    o1.w = (unsigned)f2bf(e1[6] * inv) | ((unsigned)f2bf(e1[7] * inv) << 16);
    ((uint4*)p)[c1] = o1;
  }
}

// ---------------- bf16 -> f32 expand (half of attn) ----------------
__global__ __launch_bounds__(256) void exp_k(const u16* __restrict__ src,
                                             float* __restrict__ dst) {
  size_t c = (size_t)blockIdx.x * 256 + threadIdx.x;
  if (c >= (size_t)MH * AA / 8) return;
  uint4 h = ((const uint4*)src)[c];
  float4 f0, f1;
  f0.x = bf2f(h.x & 0xffffu); f0.y = bf2f(h.x >> 16);
  f0.z = bf2f(h.y & 0xffffu); f0.w = bf2f(h.y >> 16);
  f1.x = bf2f(h.z & 0xffffu); f1.y = bf2f(h.z >> 16);
  f1.z = bf2f(h.w & 0xffffu); f1.w = bf2f(h.w >> 16);
  ((float4*)dst)[2 * c] = f0;
  ((float4*)dst)[2 * c + 1] = f1;
}

// ---------------- MFMA GEMM, B^T form, 2-phase double-buffered pipeline ----------------
// MODE 1: scores -> scattered bf16 into attP (+bias). A=baf half, Bt=attw_t, K=1408.
// MODE 2: att_feat bf16. A=attP (per local batch), Bt=baf_t, K=2784.
// MODE 3: head. A=[attf|baf] (K=2816), Bt=wt (160 rows), fused bias/sigmoid/anchor.
template <int MODE, int BN>
__global__ __launch_bounds__(256) void gemm_k(const u16* __restrict__ A1,
                                              const u16* __restrict__ A2,
                                              const u16* __restrict__ Bt,
                                              float* __restrict__ outf,
                                              u16* __restrict__ outh,
                                              const float* __restrict__ b1,
                                              const float* __restrict__ b2,
                                              const float* __restrict__ anch) {
  constexpr int K   = (MODE == 1) ? 1408 : (MODE == 2) ? 2784 : 2816;
  constexpr int NT  = K / 32;
  constexpr int LDA = (MODE == 2) ? 2784 : 1408;
  constexpr int LDB = (MODE == 1) ? 1408 : (MODE == 2) ? 2784 : 2816;
  constexpr int HN = BN / 2, NF = BN / 32;
  __shared__ __align__(16) u16 As[2][128 * 32];
  __shared__ __align__(16) u16 Bs[2][BN * 32];
  const int tid = threadIdx.x;
  const int lane = tid & 63;
  const int wm = tid >> 7, wn = (tid >> 6) & 1;
  const int m0 = blockIdx.x * 128;
  const int n0 = blockIdx.y * BN;
  const int bz = blockIdx.z;
  const int l16 = lane & 15, lq = lane >> 4;

  const u16* Ab = A1;
  const u16* Bb = Bt;
  if constexpr (MODE == 2) {
    Ab = A1 + (size_t)bz * AA * AA;
    Bb = Bt + (size_t)bz * DD * AA;
  }

  auto stage = [&](int buf, int t) {
    const int k0 = t * 32;
    const u16* Asrc = Ab;
    int kk = k0;
    if constexpr (MODE == 3) {
      Asrc = (k0 < 1408) ? A1 : A2;
      if (k0 >= 1408) kk = k0 - 1408;
    }
#pragma unroll
    for (int inst = 0; inst < 2; ++inst) {
      int c = tid + inst * 256;
      load16_lds(Asrc + (size_t)(m0 + (c >> 2)) * LDA + kk + (c & 3) * 8, &As[buf][c * 8]);
    }
    constexpr int NCH = BN * 4;
    for (int c = tid; c < NCH; c += 256)
      load16_lds(Bb + (size_t)(n0 + (c >> 2)) * LDB + k0 + (c & 3) * 8, &Bs[buf][c * 8]);
  };

  f32x4 acc[4][NF];
#pragma unroll
  for (int i = 0; i < 4; ++i)
#pragma unroll
    for (int j = 0; j < NF; ++j) acc[i][j] = 0.f;

  stage(0, 0);
  asm volatile("s_waitcnt vmcnt(0)" ::: "memory");
  __builtin_amdgcn_s_barrier();
  int cur = 0;
  for (int t = 0; t < NT; ++t) {
    if (t + 1 < NT) stage(cur ^ 1, t + 1);
    bf16x8 av[4], bv[NF];
#pragma unroll
    for (int mt = 0; mt < 4; ++mt)
      av[mt] = *(const bf16x8*)&As[cur][(wm * 64 + mt * 16 + l16) * 32 + lq * 8];
#pragma unroll
    for (int nt = 0; nt < NF; ++nt)
      bv[nt] = *(const bf16x8*)&Bs[cur][(wn * HN + nt * 16 + l16) * 32 + lq * 8];
#pragma unroll
    for (int mt = 0; mt < 4; ++mt)
#pragma unroll
      for (int nt = 0; nt < NF; ++nt)
        acc[mt][nt] = __builtin_amdgcn_mfma_f32_16x16x32_bf16(av[mt], bv[nt], acc[mt][nt], 0, 0, 0);
    asm volatile("s_waitcnt vmcnt(0)" ::: "memory");
    __builtin_amdgcn_s_barrier();
    cur ^= 1;
  }

  // ---- epilogue ----  C/D map: col = lane&15, row = (lane>>4)*4 + reg
  if constexpr (MODE == 1) {
#pragma unroll
    for (int nt = 0; nt < NF; ++nt) {
      int n = n0 + wn * HN + nt * 16 + l16;
      if (n >= AM1) continue;
      float bb = b1[n];
#pragma unroll
      for (int mt = 0; mt < 4; ++mt)
#pragma unroll
        for (int r = 0; r < 4; ++r) {
          int m = m0 + wm * 64 + mt * 16 + lq * 4 + r;
          int ii = m % AA;
          int col = n + (n >= ii);   // scatter: skip diagonal
          outh[(size_t)m * AA + col] = f2bf(acc[mt][nt][r] + bb);
        }
    }
  } else if constexpr (MODE == 2) {
#pragma unroll
    for (int mt = 0; mt < 4; ++mt)
#pragma unroll
      for (int r = 0; r < 4; ++r) {
        int m = m0 + wm * 64 + mt * 16 + lq * 4 + r;
        if (m >= AA) continue;
        size_t base = ((size_t)bz * AA + m) * DD;
#pragma unroll
        for (int nt = 0; nt < NF; ++nt)
          outh[base + n0 + wn * HN + nt * 16 + l16] = f2bf(acc[mt][nt][r]);
      }
  } else {
#pragma unroll
    for (int nt = 0; nt < NF; ++nt) {
      int n = wn * HN + nt * 16 + l16;   // n0 == 0
      if (n >= 146) continue;
#pragma unroll
      for (int mt = 0; mt < 4; ++mt)
#pragma unroll
        for (int r = 0; r < 4; ++r) {
          int m = m0 + wm * 64 + mt * 16 + lq * 4 + r;
          int ii = m % AA;
          float v = acc[mt][nt][r];
          if (n < 2) {
            outf[(size_t)m * 148 + n] = v + b1[n];
          } else {
            int rr = n - 2;
            v += b2[rr];
            if (rr >= 72) v = 1.f / (1.f + __expf(-v));
            outf[(size_t)m * 148 + 4 + rr] = anch[ii * 148 + 4 + rr] + v;
          }
        }
    }
  }
}

extern "C" void kernel_launch(void* const* d_in, const int* in_sizes, int n_in,
                              void* d_out, int out_size, void* d_ws, size_t ws_size,
                              hipStream_t stream) {
  const float* x       = (const float*)d_in[0];
  const float* conv_w  = (const float*)d_in[1];
  const float* conv_b  = (const float*)d_in[2];
  const float* attn_w  = (const float*)d_in[3];
  const float* attn_b  = (const float*)d_in[4];
  const float* cls_w   = (const float*)d_in[5];
  const float* cls_b   = (const float*)d_in[6];
  const float* reg_w   = (const float*)d_in[7];
  const float* reg_b   = (const float*)d_in[8];
  const float* anchors = (const float*)d_in[9];
  const int*   cut_xs  = (const int*)d_in[10];
  const unsigned char* inv = (const unsigned char*)d_in[11];

  float* props = (float*)d_out;
  float* attn  = props + (size_t)MT * 148;                       // f32 attn_mat out
  // attf parks in the NOT-YET-written second half of attn region (written last by exp_k h=1)
  u16* attf = (u16*)((char*)attn + (size_t)MH * AA * 4);         // 62.7 MB <= 124.0 MB free

  // workspace carve-up (~189 MiB, below the proven-safe round-1 footprint)
  char* wp = (char*)d_ws;
  auto take = [&](size_t bytes) { char* p = wp; wp += (bytes + 255) & ~(size_t)255; return p; };
  float* feats = (float*)take((size_t)450560 * 4);           // 1.8 MB
  u16* baf    = (u16*)take((size_t)MT * DD * 2);             // 62.7 MB
  u16* baft   = (u16*)take((size_t)MT * DD * 2);             // 62.7 MB
  u16* attP   = (u16*)take((size_t)4 * AA * AA * 2);         // 62.0 MB (4 batches)
  u16* attwt  = (u16*)take((size_t)2816 * 1408 * 2);         // 7.9 MB
  u16* wt     = (u16*)take((size_t)160 * 2816 * 2);          // 0.9 MB

  conv_k<<<dim3(176), 256, 0, stream>>>(x, conv_w, conv_b, feats);
  gather_k<<<dim3(MT), 128, 0, stream>>>(feats, cut_xs, inv, baf);
  tr_baf_k<<<dim3(44, 22, 8), 256, 0, stream>>>(baf, baft);
  tr_attw_k<<<dim3(44, 22), 256, 0, stream>>>(attn_w, attwt);
  wt_k<<<dim3(160), 256, 0, stream>>>(cls_w, reg_w, wt);
  anch_k<<<dim3(87), 256, 0, stream>>>(anchors, props);

  for (int h = 0; h < 2; ++h) {
    // GEMM1: scores bf16, scattered (+bias) into attP
    gemm_k<1, 128><<<dim3(87, 22), 256, 0, stream>>>(
        baf + (size_t)h * MH * DD, nullptr, attwt, nullptr, attP,
        attn_b, nullptr, nullptr);
    // softmax in place on attP (diag -> 0)
    softmax_k<<<dim3(MH), 256, 0, stream>>>(attP);
    // GEMM2: att_feat = attP @ baf (B = baf^T), 4 batches via grid z
    gemm_k<2, 128><<<dim3(22, 11, 4), 256, 0, stream>>>(
        attP, nullptr, baft + (size_t)h * 4 * DD * AA, nullptr,
        attf + (size_t)h * 4 * AA * DD, nullptr, nullptr, nullptr);
    // expand half-0 attn to f32 before attP is overwritten by half-1
    if (h == 0)
      exp_k<<<dim3(15138), 256, 0, stream>>>(attP, attn);
  }
  // GEMM3: head, fused bias + sigmoid + anchors into props (reads attf)
  gemm_k<3, 160><<<dim3(174, 1), 256, 0, stream>>>(
      attf, baf, wt, props, nullptr, cls_b, reg_b, anchors);
  // expand half-1 attn (clobbers attf region - safe, GEMM3 done)
  exp_k<<<dim3(15138), 256, 0, stream>>>(attP, attn + (size_t)MH * AA);
}

// Round 3
// 936.399 us; speedup vs baseline: 1.4573x; 1.0880x over previous
//
#include <hip/hip_runtime.h>
#include <stdint.h>

typedef __attribute__((ext_vector_type(8))) __bf16 bf16x8;
typedef __attribute__((ext_vector_type(4))) float f32x4;
typedef unsigned short u16;

#define DEV static __device__ __forceinline__

constexpr int NB = 8;           // batch
constexpr int AA = 2784;        // anchors
constexpr int AM1 = 2783;       // A-1
constexpr int DD = 1408;        // D = 64*22
constexpr int MT = NB * AA;     // 22272 total rows
constexpr int MH = MT / 2;      // 11136 rows per half (4 batches)
constexpr int KP = 2816;        // padded K / attP row stride (mult of 64)

DEV u16 f2bf(float f) {
  uint32_t u = __builtin_bit_cast(uint32_t, f);
  u += 0x7FFFu + ((u >> 16) & 1u);
  return (u16)(u >> 16);
}
DEV float bf2f(unsigned v) { return __builtin_bit_cast(float, v << 16); }

// async global->LDS, 16B per lane. LDS dest is wave-uniform base + lane*16 by HW.
DEV void load16_lds(const void* g, void* l) {
  auto gp = (const __attribute__((address_space(1))) uint32_t*)(uintptr_t)g;
  auto lp = (__attribute__((address_space(3))) uint32_t*)(uint32_t)(uintptr_t)l;
  __builtin_amdgcn_global_load_lds(gp, lp, 16, 0, 0);
}

#define VMW(n) asm volatile("s_waitcnt vmcnt(" #n ")" ::: "memory")
#define LGW0 asm volatile("s_waitcnt lgkmcnt(0)" ::: "memory")
#define BARR asm volatile("s_barrier" ::: "memory")
#define SCHB __builtin_amdgcn_sched_barrier(0)

// 16 MFMAs of one quadrant (compile-time QM/QN keep acc indices static)
template <int QM, int QN>
DEV void mfma16(f32x4 (&acc)[8][4], const bf16x8 (&Av)[4][2], const bf16x8 (&Bv)[2][2]) {
  __builtin_amdgcn_s_setprio(1);
#pragma unroll
  for (int mt = 0; mt < 4; ++mt)
#pragma unroll
    for (int nt = 0; nt < 2; ++nt)
#pragma unroll
      for (int ks = 0; ks < 2; ++ks)
        acc[QM * 4 + mt][QN * 2 + nt] = __builtin_amdgcn_mfma_f32_16x16x32_bf16(
            Av[mt][ks], Bv[nt][ks], acc[QM * 4 + mt][QN * 2 + nt], 0, 0, 0);
  __builtin_amdgcn_s_setprio(0);
}

// ---------------- 256x256 8-phase MFMA GEMM, B^T form ----------------
// MODE 1: scores = baf @ attw_t^T, scattered bf16 (+bias) into attP[.][2816]
// MODE 2: att_feat = attP @ baft^T (per batch z), bf16 out
template <int MODE>
__global__ __launch_bounds__(512) void gemm8_k(const u16* __restrict__ A,
                                               const u16* __restrict__ Bt,
                                               u16* __restrict__ outh,
                                               const float* __restrict__ b1) {
  constexpr int K   = (MODE == 1) ? 1408 : KP;
  constexpr int LDA = (MODE == 1) ? 1408 : KP;
  constexpr int LDB = (MODE == 1) ? 1408 : KP;
  constexpr int MR  = (MODE == 1) ? MH : AA;    // valid A rows
  constexpr int NRB = (MODE == 1) ? KP : 1408;  // valid B rows
  constexpr int NT2 = K / 128;                  // iterations (2 K-tiles each)
  __shared__ u16 As_[2][16384];
  __shared__ u16 Bs_[2][16384];
  const int tid = threadIdx.x;
  const int lane = tid & 63;
  const int w = tid >> 6;
  const int wr = w >> 2, wc = w & 3;
  const int l16 = lane & 15, lq = lane >> 4;
  const int m0 = blockIdx.x * 256, n0 = blockIdx.y * 256;

  const u16* Ab = A;
  const u16* Bb = Bt;
  u16* outp = outh;
  if constexpr (MODE == 2) {
    const int bz = blockIdx.z;
    Ab += (size_t)bz * AA * KP;
    Bb += (size_t)bz * 1408 * KP;
    outp += (size_t)bz * AA * 1408;
  }

  // stage one half-tile (128 rows x 64 k) with inverse-swizzled global source
  auto stA = [&](int buf, int half, int kt) {
#pragma unroll
    for (int inst = 0; inst < 2; ++inst) {
      int c = tid + inst * 512;
      int row = c >> 3, sl = c & 7;
      int sr = m0 + half * 128 + row;
      sr = sr < MR - 1 ? sr : MR - 1;
      load16_lds(Ab + (size_t)sr * LDA + kt * 64 + ((sl ^ (row & 7)) * 8),
                 &As_[buf][half * 8192 + c * 8]);
    }
  };
  auto stB = [&](int buf, int half, int kt) {
#pragma unroll
    for (int inst = 0; inst < 2; ++inst) {
      int c = tid + inst * 512;
      int row = c >> 3, sl = c & 7;
      int sr = n0 + half * 128 + row;
      sr = sr < NRB - 1 ? sr : NRB - 1;
      load16_lds(Bb + (size_t)sr * LDB + kt * 64 + ((sl ^ (row & 7)) * 8),
                 &Bs_[buf][half * 8192 + c * 8]);
    }
  };
  // swizzled ds_reads of MFMA fragments
  auto rdA = [&](int buf, int qm, bf16x8 (&a)[4][2]) {
#pragma unroll
    for (int mt = 0; mt < 4; ++mt)
#pragma unroll
      for (int ks = 0; ks < 2; ++ks) {
        int row = wr * 128 + qm * 64 + mt * 16 + l16;
        int ch = (ks * 4 + lq) ^ (row & 7);
        a[mt][ks] = *(const bf16x8*)&As_[buf][row * 64 + ch * 8];
      }
  };
  auto rdB = [&](int buf, int qn, bf16x8 (&b)[2][2]) {
#pragma unroll
    for (int nt = 0; nt < 2; ++nt)
#pragma unroll
      for (int ks = 0; ks < 2; ++ks) {
        int row = wc * 64 + qn * 32 + nt * 16 + l16;
        int ch = (ks * 4 + lq) ^ (row & 7);
        b[nt][ks] = *(const bf16x8*)&Bs_[buf][row * 64 + ch * 8];
      }
  };

  f32x4 acc[8][4];
#pragma unroll
  for (int i = 0; i < 8; ++i)
#pragma unroll
    for (int j = 0; j < 4; ++j) acc[i][j] = 0.f;

  bf16x8 aL[4][2], aH[4][2], bL[2][2], bH[2][2];

  // prologue: buf0 <- kt0 (all 4 halves), buf1 <- kt1 {Alo,Blo,Bhi}; P0 adds Ahi
  stA(0, 0, 0); stA(0, 1, 0); stB(0, 0, 0); stB(0, 1, 0);
  stA(1, 0, 1); stB(1, 0, 1); stB(1, 1, 1);
  VMW(6);
  BARR;

  for (int t = 0; t < NT2; ++t) {
    const int kt0 = 2 * t, kt1 = 2 * t + 1;
    const bool tail = (t == NT2 - 1);
    // P0: reads b0 {Alo quad, Blo quad}; stage b1.Ahi <- A1(kt1)
    rdA(0, 0, aL); rdB(0, 0, bL);
    stA(1, 1, kt1);
    BARR; LGW0; SCHB;
    mfma16<0, 0>(acc, aL, bL);
    BARR;
    // P1: read b0 Bhi-quad; stage b0.Alo <- A0(kt0+2)
    rdB(0, 1, bH);
    if (!tail) stA(0, 0, kt0 + 2);
    BARR; LGW0; SCHB;
    mfma16<0, 1>(acc, aL, bH);
    BARR;
    // P2: read b0 Ahi-quad; stage b0.Blo
    rdA(0, 1, aH);
    if (!tail) stB(0, 0, kt0 + 2);
    BARR; LGW0; SCHB;
    mfma16<1, 0>(acc, aH, bL);
    BARR;
    // P3: stage b0.Bhi; counted wait -> buf1 fully staged before P4 reads
    if (!tail) { stB(0, 1, kt0 + 2); VMW(6); } else { VMW(0); }
    BARR; SCHB;
    mfma16<1, 1>(acc, aH, bH);
    BARR;
    // P4: reads b1 {Alo,Blo}; stage b0.Ahi
    rdA(1, 0, aL); rdB(1, 0, bL);
    if (!tail) stA(0, 1, kt0 + 2);
    BARR; LGW0; SCHB;
    mfma16<0, 0>(acc, aL, bL);
    BARR;
    // P5: read b1 Bhi; stage b1.Alo <- A0(kt1+2)
    rdB(1, 1, bH);
    if (!tail) stA(1, 0, kt1 + 2);
    BARR; LGW0; SCHB;
    mfma16<0, 1>(acc, aL, bH);
    BARR;
    // P6: read b1 Ahi; stage b1.Blo
    rdA(1, 1, aH);
    if (!tail) stB(1, 0, kt1 + 2);
    BARR; LGW0; SCHB;
    mfma16<1, 0>(acc, aH, bL);
    BARR;
    // P7: stage b1.Bhi; counted wait -> buf0(kt0+2) staged through A1 for next P0-P2
    if (!tail) { stB(1, 1, kt1 + 2); VMW(6); }
    BARR; SCHB;
    mfma16<1, 1>(acc, aH, bH);
    BARR;
  }

  // ---- epilogue ----  C/D map: col = lane&15, row = (lane>>4)*4 + reg
  if constexpr (MODE == 1) {
#pragma unroll
    for (int mi = 0; mi < 8; ++mi)
#pragma unroll
      for (int r = 0; r < 4; ++r) {
        int m = m0 + wr * 128 + mi * 16 + lq * 4 + r;
        if (m >= MR) continue;
        int ii = m % AA;
#pragma unroll
        for (int ni = 0; ni < 4; ++ni) {
          int n = n0 + wc * 64 + ni * 16 + l16;
          if (n >= AM1) continue;
          int col = n + (n >= ii);  // scatter: skip diagonal
          outp[(size_t)m * KP + col] = f2bf(acc[mi][ni][r] + b1[n]);
        }
      }
  } else {
#pragma unroll
    for (int mi = 0; mi < 8; ++mi)
#pragma unroll
      for (int r = 0; r < 4; ++r) {
        int m = m0 + wr * 128 + mi * 16 + lq * 4 + r;
        if (m >= AA) continue;
        size_t base = (size_t)m * 1408;
#pragma unroll
        for (int ni = 0; ni < 4; ++ni) {
          int n = n0 + wc * 64 + ni * 16 + l16;
          if (n < 1408) outp[base + n] = f2bf(acc[mi][ni][r]);
        }
      }
  }
}

// ---------------- 1x1 conv: feats[b][o][h][w] ----------------
__global__ __launch_bounds__(256) void conv_k(const float* __restrict__ x,
                                              const float* __restrict__ w,
                                              const float* __restrict__ bias,
                                              float* __restrict__ feats) {
  __shared__ float xs[256 * 40];
  int bb = blockIdx.x / 22, h = blockIdx.x % 22;
  const float* xp = x + (size_t)bb * 256 * 880 + h * 40;
  for (int l = threadIdx.x; l < 256 * 40; l += 256)
    xs[l] = xp[(l / 40) * 880 + (l % 40)];
  __syncthreads();
  for (int l = threadIdx.x; l < 64 * 40; l += 256) {
    int o = l / 40, ww = l % 40;
    float acc = bias[o];
    const float* wr = w + o * 256;
#pragma unroll 8
    for (int c = 0; c < 256; ++c) acc += xs[c * 40 + ww] * wr[c];
    feats[((size_t)(bb * 64 + o) * 22 + h) * 40 + ww] = acc;
  }
}

// ---------------- gather + mask -> baf bf16 (B,A,D) ----------------
__global__ __launch_bounds__(128) void gather_k(const float* __restrict__ feats,
                                                const int* __restrict__ cut,
                                                const unsigned char* __restrict__ inv,
                                                u16* __restrict__ baf) {
  unsigned probe = 0;
#pragma unroll
  for (int t = 0; t < 10; ++t)
    probe |= (unsigned)inv[4 * t + 1] | (unsigned)inv[4 * t + 2] | (unsigned)inv[4 * t + 3];
  const bool is_u8 = (probe != 0);  // i32 storage -> high bytes all zero
  int ba = blockIdx.x;
  int b = ba / AA, a = ba - (ba / AA) * AA;
  for (int d = threadIdx.x; d < DD; d += 128) {
    int o = d / 22, h = d - o * 22;
    int msk = is_u8 ? (int)inv[a * 22 + h] : ((const int*)inv)[a * 22 + h];
    float v = 0.f;
    if (!msk) v = feats[((size_t)(b * 64 + o) * 22 + h) * 40 + cut[a * 22 + h]];
    baf[(size_t)ba * DD + d] = f2bf(v);
  }
}

// ---------------- baf (B,A,D) -> baf_t (B,D,A+pad), stride KP ----------------
__global__ __launch_bounds__(256) void tr_baf_k(const u16* __restrict__ baf,
                                                u16* __restrict__ bft) {
  __shared__ u16 t[64][65];
  int a0 = blockIdx.x * 64, d0 = blockIdx.y * 64, b = blockIdx.z;
  int tx = threadIdx.x & 63, ty = threadIdx.x >> 6;
  for (int r = ty; r < 64; r += 4) {
    int a = a0 + r;
    t[r][tx] = (a < AA) ? baf[((size_t)b * AA + a) * DD + d0 + tx] : (u16)0;
  }
  __syncthreads();
  for (int r = ty; r < 64; r += 4) {
    int a = a0 + tx;
    if (a < AA) bft[((size_t)b * DD + d0 + r) * KP + a] = t[tx][r];
  }
}

// ---------------- attn_w (1408,2783) f32 -> attw_t (2816,1408) bf16, zero pad ----------------
__global__ __launch_bounds__(256) void tr_attw_k(const float* __restrict__ w,
                                                 u16* __restrict__ wt) {
  __shared__ u16 t[64][65];
  int n0 = blockIdx.x * 64, k0 = blockIdx.y * 64;
  int tx = threadIdx.x & 63, ty = threadIdx.x >> 6;
  for (int r = ty; r < 64; r += 4) {
    int n = n0 + tx;
    t[r][tx] = (n < AM1) ? f2bf(w[(size_t)(k0 + r) * AM1 + n]) : (u16)0;
  }
  __syncthreads();
  for (int r = ty; r < 64; r += 4)
    wt[(size_t)(n0 + r) * 1408 + k0 + tx] = t[tx][r];
}

// ---------------- pack head weights: wt[n][k], n<2 cls, 2..145 reg, pad->160 ----------------
__global__ __launch_bounds__(256) void wt_k(const float* __restrict__ cw,
                                            const float* __restrict__ rw,
                                            u16* __restrict__ wt) {
  int n = blockIdx.x;
  for (int k = threadIdx.x; k < 2816; k += 256) {
    float v = 0.f;
    if (n < 2) v = cw[(size_t)k * 2 + n];
    else if (n < 146) v = rw[(size_t)k * 144 + (n - 2)];
    wt[(size_t)n * 2816 + k] = f2bf(v);
  }
}

// ---------------- props cols 2,3 = anchors[:,2:4] ----------------
__global__ __launch_bounds__(256) void anch_k(const float* __restrict__ anch,
                                              float* __restrict__ props) {
  int idx = blockIdx.x * 256 + threadIdx.x;
  if (idx >= MT) return;
  int a = idx % AA;
  props[(size_t)idx * 148 + 2] = anch[a * 148 + 2];
  props[(size_t)idx * 148 + 3] = anch[a * 148 + 3];
}

// ---------------- in-place row softmax on scattered bf16 attP rows (stride KP) ----------------
__global__ __launch_bounds__(256) void softmax_k(u16* __restrict__ attP) {
  const int row = blockIdx.x;            // 0..MH-1
  const int i = row % AA;
  u16* p = attP + (size_t)row * KP;
  const int tid = threadIdx.x;
  const int c0 = tid, c1 = tid + 256;    // 352 chunks of 8 (incl. 4 pad chunks)
  const bool has1 = (c1 < 352);
  uint4 h0 = ((const uint4*)p)[c0];
  uint4 h1 = has1 ? ((const uint4*)p)[c1] : make_uint4(0, 0, 0, 0);
  float v0[8], v1[8];
  v0[0] = bf2f(h0.x & 0xffffu); v0[1] = bf2f(h0.x >> 16);
  v0[2] = bf2f(h0.y & 0xffffu); v0[3] = bf2f(h0.y >> 16);
  v0[4] = bf2f(h0.z & 0xffffu); v0[5] = bf2f(h0.z >> 16);
  v0[6] = bf2f(h0.w & 0xffffu); v0[7] = bf2f(h0.w >> 16);
  v1[0] = bf2f(h1.x & 0xffffu); v1[1] = bf2f(h1.x >> 16);
  v1[2] = bf2f(h1.y & 0xffffu); v1[3] = bf2f(h1.y >> 16);
  v1[4] = bf2f(h1.z & 0xffffu); v1[5] = bf2f(h1.z >> 16);
  v1[6] = bf2f(h1.w & 0xffffu); v1[7] = bf2f(h1.w >> 16);
  float mx = -3e38f;
#pragma unroll
  for (int e = 0; e < 8; ++e) { int j = c0 * 8 + e; if (j < AA && j != i) mx = fmaxf(mx, v0[e]); }
#pragma unroll
  for (int e = 0; e < 8; ++e) { int j = c1 * 8 + e; if (has1 && j < AA && j != i) mx = fmaxf(mx, v1[e]); }
#pragma unroll
  for (int o = 1; o < 64; o <<= 1) mx = fmaxf(mx, __shfl_xor(mx, o));
  __shared__ float rm[4], rs[4];
  if (!(tid & 63)) rm[tid >> 6] = mx;
  __syncthreads();
  mx = fmaxf(fmaxf(rm[0], rm[1]), fmaxf(rm[2], rm[3]));
  float s = 0.f, e0[8], e1[8];
#pragma unroll
  for (int e = 0; e < 8; ++e) {
    int j = c0 * 8 + e;
    float t = (j < AA && j != i) ? __expf(v0[e] - mx) : 0.f;
    e0[e] = t; s += t;
  }
#pragma unroll
  for (int e = 0; e < 8; ++e) {
    int j = c1 * 8 + e;
    float t = (has1 && j < AA && j != i) ? __expf(v1[e] - mx) : 0.f;
    e1[e] = t; s += t;
  }
#pragma unroll
  for (int o = 1; o < 64; o <<= 1) s += __shfl_xor(s, o);
  if (!(tid & 63)) rs[tid >> 6] = s;
  __syncthreads();
  s = (rs[0] + rs[1]) + (rs[2] + rs[3]);
  const float inv = 1.f / s;
  uint4 o0, o1;
  o0.x = (unsigned)f2bf(e0[0] * inv) | ((unsigned)f2bf(e0[1] * inv) << 16);
  o0.y = (unsigned)f2bf(e0[2] * inv) | ((unsigned)f2bf(e0[3] * inv) << 16);
  o0.z = (unsigned)f2bf(e0[4] * inv) | ((unsigned)f2bf(e0[5] * inv) << 16);
  o0.w = (unsigned)f2bf(e0[6] * inv) | ((unsigned)f2bf(e0[7] * inv) << 16);
  ((uint4*)p)[c0] = o0;
  if (has1) {
    o1.x = (unsigned)f2bf(e1[0] * inv) | ((unsigned)f2bf(e1[1] * inv) << 16);
    o1.y = (unsigned)f2bf(e1[2] * inv) | ((unsigned)f2bf(e1[3] * inv) << 16);
    o1.z = (unsigned)f2bf(e1[4] * inv) | ((unsigned)f2bf(e1[5] * inv) << 16);
    o1.w = (unsigned)f2bf(e1[6] * inv) | ((unsigned)f2bf(e1[7] * inv) << 16);
    ((uint4*)p)[c1] = o1;
  }
}

// ---------------- bf16 (stride KP) -> f32 (stride AA) expand ----------------
__global__ __launch_bounds__(256) void exp_k(const u16* __restrict__ src,
                                             float* __restrict__ dst) {
  int row = blockIdx.y;
  int cc = blockIdx.x * 256 + threadIdx.x;
  if (cc >= 348) return;
  uint4 h = ((const uint4*)(src + (size_t)row * KP))[cc];
  float4 f0, f1;
  f0.x = bf2f(h.x & 0xffffu); f0.y = bf2f(h.x >> 16);
  f0.z = bf2f(h.y & 0xffffu); f0.w = bf2f(h.y >> 16);
  f1.x = bf2f(h.z & 0xffffu); f1.y = bf2f(h.z >> 16);
  f1.z = bf2f(h.w & 0xffffu); f1.w = bf2f(h.w >> 16);
  float4* dp = (float4*)(dst + (size_t)row * AA);
  dp[2 * cc] = f0;
  dp[2 * cc + 1] = f1;
}

// ---------------- head GEMM (2-phase, BN=160): [attf|baf] @ wt^T, fused epilogue ----------------
__global__ __launch_bounds__(256) void head_k(const u16* __restrict__ A1,
                                              const u16* __restrict__ A2,
                                              const u16* __restrict__ Bt,
                                              float* __restrict__ outf,
                                              const float* __restrict__ b1,
                                              const float* __restrict__ b2,
                                              const float* __restrict__ anch) {
  constexpr int K = 2816, NT = K / 32, BN = 160, HN = 80, NF = 5;
  __shared__ __align__(16) u16 As[2][128 * 32];
  __shared__ __align__(16) u16 Bs[2][BN * 32];
  const int tid = threadIdx.x;
  const int lane = tid & 63;
  const int wm = tid >> 7, wn = (tid >> 6) & 1;
  const int m0 = blockIdx.x * 128;
  const int l16 = lane & 15, lq = lane >> 4;

  auto stage = [&](int buf, int t) {
    const int k0 = t * 32;
    const u16* Asrc = (k0 < 1408) ? A1 : A2;
    const int kk = (k0 < 1408) ? k0 : k0 - 1408;
#pragma unroll
    for (int inst = 0; inst < 2; ++inst) {
      int c = tid + inst * 256;
      load16_lds(Asrc + (size_t)(m0 + (c >> 2)) * 1408 + kk + (c & 3) * 8, &As[buf][c * 8]);
    }
    for (int c = tid; c < BN * 4; c += 256)
      load16_lds(Bt + (size_t)(c >> 2) * K + k0 + (c & 3) * 8, &Bs[buf][c * 8]);
  };

  f32x4 acc[4][NF];
#pragma unroll
  for (int i = 0; i < 4; ++i)
#pragma unroll
    for (int j = 0; j < NF; ++j) acc[i][j] = 0.f;

  stage(0, 0);
  asm volatile("s_waitcnt vmcnt(0)" ::: "memory");
  __builtin_amdgcn_s_barrier();
  int cur = 0;
  for (int t = 0; t < NT; ++t) {
    if (t + 1 < NT) stage(cur ^ 1, t + 1);
    bf16x8 av[4], bv[NF];
#pragma unroll
    for (int mt = 0; mt < 4; ++mt)
      av[mt] = *(const bf16x8*)&As[cur][(wm * 64 + mt * 16 + l16) * 32 + lq * 8];
#pragma unroll
    for (int nt = 0; nt < NF; ++nt)
      bv[nt] = *(const bf16x8*)&Bs[cur][(wn * HN + nt * 16 + l16) * 32 + lq * 8];
#pragma unroll
    for (int mt = 0; mt < 4; ++mt)
#pragma unroll
      for (int nt = 0; nt < NF; ++nt)
        acc[mt][nt] = __builtin_amdgcn_mfma_f32_16x16x32_bf16(av[mt], bv[nt], acc[mt][nt], 0, 0, 0);
    asm volatile("s_waitcnt vmcnt(0)" ::: "memory");
    __builtin_amdgcn_s_barrier();
    cur ^= 1;
  }

#pragma unroll
  for (int nt = 0; nt < NF; ++nt) {
    int n = wn * HN + nt * 16 + l16;
    if (n >= 146) continue;
#pragma unroll
    for (int mt = 0; mt < 4; ++mt)
#pragma unroll
      for (int r = 0; r < 4; ++r) {
        int m = m0 + wm * 64 + mt * 16 + lq * 4 + r;
        int ii = m % AA;
        float v = acc[mt][nt][r];
        if (n < 2) {
          outf[(size_t)m * 148 + n] = v + b1[n];
        } else {
          int rr = n - 2;
          v += b2[rr];
          if (rr >= 72) v = 1.f / (1.f + __expf(-v));
          outf[(size_t)m * 148 + 4 + rr] = anch[ii * 148 + 4 + rr] + v;
        }
      }
  }
}

extern "C" void kernel_launch(void* const* d_in, const int* in_sizes, int n_in,
                              void* d_out, int out_size, void* d_ws, size_t ws_size,
                              hipStream_t stream) {
  const float* x       = (const float*)d_in[0];
  const float* conv_w  = (const float*)d_in[1];
  const float* conv_b  = (const float*)d_in[2];
  const float* attn_w  = (const float*)d_in[3];
  const float* attn_b  = (const float*)d_in[4];
  const float* cls_w   = (const float*)d_in[5];
  const float* cls_b   = (const float*)d_in[6];
  const float* reg_w   = (const float*)d_in[7];
  const float* reg_b   = (const float*)d_in[8];
  const float* anchors = (const float*)d_in[9];
  const int*   cut_xs  = (const int*)d_in[10];
  const unsigned char* inv = (const unsigned char*)d_in[11];

  float* props = (float*)d_out;
  float* attn  = props + (size_t)MT * 148;                   // f32 attn_mat out
  // park attf + feats + wt in the not-yet-written second half of attn
  // (written last by exp_k h=1, after all readers are done)
  u16* attf    = (u16*)((char*)attn + (size_t)MH * AA * 4);  // 62.7 MB
  char* park   = (char*)attf + (size_t)MT * DD * 2;
  float* feats = (float*)park;                               // 1.8 MB
  u16* wt      = (u16*)(park + 4 * 1024 * 1024);             // 0.9 MB

  // workspace carve-up (~197 MB, below the proven round-1/2 footprint)
  char* wp = (char*)d_ws;
  auto take = [&](size_t bytes) { char* p = wp; wp += (bytes + 255) & ~(size_t)255; return p; };
  u16* baf   = (u16*)take((size_t)MT * DD * 2);              // 62.7 MB
  u16* baft  = (u16*)take((size_t)NB * DD * KP * 2);         // 63.4 MB (stride KP)
  u16* attP  = (u16*)take((size_t)MH * KP * 2);              // 62.7 MB (4 batches, stride KP)
  u16* attwt = (u16*)take((size_t)KP * 1408 * 2);            // 7.9 MB

  conv_k<<<dim3(176), 256, 0, stream>>>(x, conv_w, conv_b, feats);
  gather_k<<<dim3(MT), 128, 0, stream>>>(feats, cut_xs, inv, baf);
  tr_baf_k<<<dim3(44, 22, 8), 256, 0, stream>>>(baf, baft);
  tr_attw_k<<<dim3(44, 22), 256, 0, stream>>>(attn_w, attwt);
  wt_k<<<dim3(160), 256, 0, stream>>>(cls_w, reg_w, wt);
  anch_k<<<dim3(87), 256, 0, stream>>>(anchors, props);

  for (int h = 0; h < 2; ++h) {
    // GEMM1: scores bf16, scattered (+bias) into attP (8-phase 256^2)
    gemm8_k<1><<<dim3(44, 11), 512, 0, stream>>>(
        baf + (size_t)h * MH * DD, attwt, attP, attn_b);
    // softmax in place on attP (diag -> 0, zero K-pad)
    softmax_k<<<dim3(MH), 256, 0, stream>>>(attP);
    // GEMM2: att_feat = attP @ baf^T, 4 batches via grid z (8-phase 256^2)
    gemm8_k<2><<<dim3(11, 6, 4), 512, 0, stream>>>(
        attP, baft + (size_t)h * 4 * DD * KP,
        attf + (size_t)h * 4 * AA * DD, nullptr);
    // expand half-0 attn to f32 before attP is overwritten by half-1
    if (h == 0)
      exp_k<<<dim3(2, MH), 256, 0, stream>>>(attP, attn);
  }
  // head GEMM: fused bias + sigmoid + anchors into props (reads attf)
  head_k<<<dim3(174), 256, 0, stream>>>(attf, baf, wt, props,
                                        cls_b, reg_b, anchors);
  // expand half-1 attn (clobbers attf/park region - safe, head_k done)
  exp_k<<<dim3(2, MH), 256, 0, stream>>>(attP, attn + (size_t)MH * AA);
}

// Round 4
// 891.018 us; speedup vs baseline: 1.5315x; 1.0509x over previous
//
#include <hip/hip_runtime.h>
#include <stdint.h>

typedef __attribute__((ext_vector_type(8))) __bf16 bf16x8;
typedef __attribute__((ext_vector_type(4))) float f32x4;
typedef unsigned short u16;

#define DEV static __device__ __forceinline__

constexpr int NB = 8;           // batch
constexpr int AA = 2784;        // anchors
constexpr int AM1 = 2783;       // A-1
constexpr int DD = 1408;        // D = 64*22
constexpr int MT = NB * AA;     // 22272 total rows
constexpr int MH = MT / 2;      // 11136 rows per half (4 batches)
constexpr int KP = 2816;        // padded K / attP row stride (mult of 64)

DEV u16 f2bf(float f) {
  uint32_t u = __builtin_bit_cast(uint32_t, f);
  u += 0x7FFFu + ((u >> 16) & 1u);
  return (u16)(u >> 16);
}
DEV float bf2f(unsigned v) { return __builtin_bit_cast(float, v << 16); }

// async global->LDS, 16B per lane. LDS dest is wave-uniform base + lane*16 by HW.
DEV void load16_lds(const void* g, void* l) {
  auto gp = (const __attribute__((address_space(1))) uint32_t*)(uintptr_t)g;
  auto lp = (__attribute__((address_space(3))) uint32_t*)(uint32_t)(uintptr_t)l;
  __builtin_amdgcn_global_load_lds(gp, lp, 16, 0, 0);
}

#define VMW(n) asm volatile("s_waitcnt vmcnt(" #n ")" ::: "memory")
#define LGW0 asm volatile("s_waitcnt lgkmcnt(0)" ::: "memory")
#define BARR asm volatile("s_barrier" ::: "memory")
#define SCHB __builtin_amdgcn_sched_barrier(0)

// 16 MFMAs of one quadrant (compile-time QM/QN keep acc indices static)
template <int QM, int QN>
DEV void mfma16(f32x4 (&acc)[8][4], const bf16x8 (&Av)[4][2], const bf16x8 (&Bv)[2][2]) {
  __builtin_amdgcn_s_setprio(1);
#pragma unroll
  for (int mt = 0; mt < 4; ++mt)
#pragma unroll
    for (int nt = 0; nt < 2; ++nt)
#pragma unroll
      for (int ks = 0; ks < 2; ++ks)
        acc[QM * 4 + mt][QN * 2 + nt] = __builtin_amdgcn_mfma_f32_16x16x32_bf16(
            Av[mt][ks], Bv[nt][ks], acc[QM * 4 + mt][QN * 2 + nt], 0, 0, 0);
  __builtin_amdgcn_s_setprio(0);
}

// ---------------- 256x256 8-phase MFMA GEMM, B^T form ----------------
// MODE 1: scores = baf @ attw_t^T, scattered bf16 (+bias) into attP[.][2816]
// MODE 2: att_feat = attP @ baft^T (per batch z), bf16 out
template <int MODE>
__global__ __launch_bounds__(512) void gemm8_k(const u16* __restrict__ A,
                                               const u16* __restrict__ Bt,
                                               u16* __restrict__ outh,
                                               const float* __restrict__ b1) {
  constexpr int K   = (MODE == 1) ? 1408 : KP;
  constexpr int LDA = (MODE == 1) ? 1408 : KP;
  constexpr int LDB = (MODE == 1) ? 1408 : KP;
  constexpr int MR  = (MODE == 1) ? MH : AA;    // valid A rows
  constexpr int NRB = (MODE == 1) ? KP : 1408;  // valid B rows
  constexpr int NT2 = K / 128;                  // iterations (2 K-tiles each)
  __shared__ u16 As_[2][16384];
  __shared__ u16 Bs_[2][16384];
  const int tid = threadIdx.x;
  const int lane = tid & 63;
  const int w = tid >> 6;
  const int wr = w >> 2, wc = w & 3;
  const int l16 = lane & 15, lq = lane >> 4;

  // T1: bijective XCD swizzle (m204). HW dispatch order i -> XCD ~ i%8.
  // Give each XCD a contiguous logical-chunk, y-fastest so co-resident
  // blocks on one XCD share A panels (and a small B panel set) in its L2.
  const int gx = gridDim.x, gy = gridDim.y;
  const int nwg = gx * gy;
  const int i = blockIdx.x + blockIdx.y * gx;
  const int xcd = i & 7, pos = i >> 3;
  const int q = nwg >> 3, r = nwg & 7;
  const int lid = (xcd < r ? xcd * (q + 1) : r * (q + 1) + (xcd - r) * q) + pos;
  const int m0 = (lid / gy) * 256, n0 = (lid % gy) * 256;

  const u16* Ab = A;
  const u16* Bb = Bt;
  u16* outp = outh;
  if constexpr (MODE == 2) {
    const int bz = blockIdx.z;
    Ab += (size_t)bz * AA * KP;
    Bb += (size_t)bz * 1408 * KP;
    outp += (size_t)bz * AA * 1408;
  }

  // stage one half-tile (128 rows x 64 k) with inverse-swizzled global source
  auto stA = [&](int buf, int half, int kt) {
#pragma unroll
    for (int inst = 0; inst < 2; ++inst) {
      int c = tid + inst * 512;
      int row = c >> 3, sl = c & 7;
      int sr = m0 + half * 128 + row;
      sr = sr < MR - 1 ? sr : MR - 1;
      load16_lds(Ab + (size_t)sr * LDA + kt * 64 + ((sl ^ (row & 7)) * 8),
                 &As_[buf][half * 8192 + c * 8]);
    }
  };
  auto stB = [&](int buf, int half, int kt) {
#pragma unroll
    for (int inst = 0; inst < 2; ++inst) {
      int c = tid + inst * 512;
      int row = c >> 3, sl = c & 7;
      int sr = n0 + half * 128 + row;
      sr = sr < NRB - 1 ? sr : NRB - 1;
      load16_lds(Bb + (size_t)sr * LDB + kt * 64 + ((sl ^ (row & 7)) * 8),
                 &Bs_[buf][half * 8192 + c * 8]);
    }
  };
  // swizzled ds_reads of MFMA fragments
  auto rdA = [&](int buf, int qm, bf16x8 (&a)[4][2]) {
#pragma unroll
    for (int mt = 0; mt < 4; ++mt)
#pragma unroll
      for (int ks = 0; ks < 2; ++ks) {
        int row = wr * 128 + qm * 64 + mt * 16 + l16;
        int ch = (ks * 4 + lq) ^ (row & 7);
        a[mt][ks] = *(const bf16x8*)&As_[buf][row * 64 + ch * 8];
      }
  };
  auto rdB = [&](int buf, int qn, bf16x8 (&b)[2][2]) {
#pragma unroll
    for (int nt = 0; nt < 2; ++nt)
#pragma unroll
      for (int ks = 0; ks < 2; ++ks) {
        int row = wc * 64 + qn * 32 + nt * 16 + l16;
        int ch = (ks * 4 + lq) ^ (row & 7);
        b[nt][ks] = *(const bf16x8*)&Bs_[buf][row * 64 + ch * 8];
      }
  };

  f32x4 acc[8][4];
#pragma unroll
  for (int i2 = 0; i2 < 8; ++i2)
#pragma unroll
    for (int j = 0; j < 4; ++j) acc[i2][j] = 0.f;

  bf16x8 aL[4][2], aH[4][2], bL[2][2], bH[2][2];

  // prologue: buf0 <- kt0 (all 4 halves), buf1 <- kt1 {Alo,Blo,Bhi}; P0 adds Ahi
  stA(0, 0, 0); stA(0, 1, 0); stB(0, 0, 0); stB(0, 1, 0);
  stA(1, 0, 1); stB(1, 0, 1); stB(1, 1, 1);
  VMW(6);
  BARR;

  for (int t = 0; t < NT2; ++t) {
    const int kt0 = 2 * t, kt1 = 2 * t + 1;
    const bool tail = (t == NT2 - 1);
    // P0: reads b0 {Alo quad, Blo quad}; stage b1.Ahi <- A1(kt1)
    rdA(0, 0, aL); rdB(0, 0, bL);
    stA(1, 1, kt1);
    BARR; LGW0; SCHB;
    mfma16<0, 0>(acc, aL, bL);
    BARR;
    // P1: read b0 Bhi-quad; stage b0.Alo <- A0(kt0+2)
    rdB(0, 1, bH);
    if (!tail) stA(0, 0, kt0 + 2);
    BARR; LGW0; SCHB;
    mfma16<0, 1>(acc, aL, bH);
    BARR;
    // P2: read b0 Ahi-quad; stage b0.Blo
    rdA(0, 1, aH);
    if (!tail) stB(0, 0, kt0 + 2);
    BARR; LGW0; SCHB;
    mfma16<1, 0>(acc, aH, bL);
    BARR;
    // P3: stage b0.Bhi; counted wait -> buf1 fully staged before P4 reads
    if (!tail) { stB(0, 1, kt0 + 2); VMW(6); } else { VMW(0); }
    BARR; SCHB;
    mfma16<1, 1>(acc, aH, bH);
    BARR;
    // P4: reads b1 {Alo,Blo}; stage b0.Ahi
    rdA(1, 0, aL); rdB(1, 0, bL);
    if (!tail) stA(0, 1, kt0 + 2);
    BARR; LGW0; SCHB;
    mfma16<0, 0>(acc, aL, bL);
    BARR;
    // P5: read b1 Bhi; stage b1.Alo <- A0(kt1+2)
    rdB(1, 1, bH);
    if (!tail) stA(1, 0, kt1 + 2);
    BARR; LGW0; SCHB;
    mfma16<0, 1>(acc, aL, bH);
    BARR;
    // P6: read b1 Ahi; stage b1.Blo
    rdA(1, 1, aH);
    if (!tail) stB(1, 0, kt1 + 2);
    BARR; LGW0; SCHB;
    mfma16<1, 0>(acc, aH, bL);
    BARR;
    // P7: stage b1.Bhi; counted wait -> buf0(kt0+2) staged through A1 for next P0-P2
    if (!tail) { stB(1, 1, kt1 + 2); VMW(6); }
    BARR; SCHB;
    mfma16<1, 1>(acc, aH, bH);
    BARR;
  }

  // ---- epilogue ----  C/D map: col = lane&15, row = (lane>>4)*4 + reg
  if constexpr (MODE == 1) {
#pragma unroll
    for (int mi = 0; mi < 8; ++mi)
#pragma unroll
      for (int r2 = 0; r2 < 4; ++r2) {
        int m = m0 + wr * 128 + mi * 16 + lq * 4 + r2;
        if (m >= MR) continue;
        int ii = m % AA;
#pragma unroll
        for (int ni = 0; ni < 4; ++ni) {
          int n = n0 + wc * 64 + ni * 16 + l16;
          if (n >= AM1) continue;
          int col = n + (n >= ii);  // scatter: skip diagonal
          outp[(size_t)m * KP + col] = f2bf(acc[mi][ni][r2] + b1[n]);
        }
      }
  } else {
#pragma unroll
    for (int mi = 0; mi < 8; ++mi)
#pragma unroll
      for (int r2 = 0; r2 < 4; ++r2) {
        int m = m0 + wr * 128 + mi * 16 + lq * 4 + r2;
        if (m >= AA) continue;
        size_t base = (size_t)m * 1408;
#pragma unroll
        for (int ni = 0; ni < 4; ++ni) {
          int n = n0 + wc * 64 + ni * 16 + l16;
          if (n < 1408) outp[base + n] = f2bf(acc[mi][ni][r2]);
        }
      }
  }
}

// ---------------- 1x1 conv: feats[b][o][h][w] ----------------
__global__ __launch_bounds__(256) void conv_k(const float* __restrict__ x,
                                              const float* __restrict__ w,
                                              const float* __restrict__ bias,
                                              float* __restrict__ feats) {
  __shared__ float xs[256 * 40];
  int bb = blockIdx.x / 22, h = blockIdx.x % 22;
  const float* xp = x + (size_t)bb * 256 * 880 + h * 40;
  for (int l = threadIdx.x; l < 256 * 40; l += 256)
    xs[l] = xp[(l / 40) * 880 + (l % 40)];
  __syncthreads();
  for (int l = threadIdx.x; l < 64 * 40; l += 256) {
    int o = l / 40, ww = l % 40;
    float acc = bias[o];
    const float* wr = w + o * 256;
#pragma unroll 8
    for (int c = 0; c < 256; ++c) acc += xs[c * 40 + ww] * wr[c];
    feats[((size_t)(bb * 64 + o) * 22 + h) * 40 + ww] = acc;
  }
}

// ---------------- gather + mask -> baf bf16 (B,A,D) ----------------
__global__ __launch_bounds__(128) void gather_k(const float* __restrict__ feats,
                                                const int* __restrict__ cut,
                                                const unsigned char* __restrict__ inv,
                                                u16* __restrict__ baf) {
  unsigned probe = 0;
#pragma unroll
  for (int t = 0; t < 10; ++t)
    probe |= (unsigned)inv[4 * t + 1] | (unsigned)inv[4 * t + 2] | (unsigned)inv[4 * t + 3];
  const bool is_u8 = (probe != 0);  // i32 storage -> high bytes all zero
  int ba = blockIdx.x;
  int b = ba / AA, a = ba - (ba / AA) * AA;
  for (int d = threadIdx.x; d < DD; d += 128) {
    int o = d / 22, h = d - o * 22;
    int msk = is_u8 ? (int)inv[a * 22 + h] : ((const int*)inv)[a * 22 + h];
    float v = 0.f;
    if (!msk) v = feats[((size_t)(b * 64 + o) * 22 + h) * 40 + cut[a * 22 + h]];
    baf[(size_t)ba * DD + d] = f2bf(v);
  }
}

// ---------------- baf (B,A,D) -> baf_t (B,D,A+pad), stride KP ----------------
__global__ __launch_bounds__(256) void tr_baf_k(const u16* __restrict__ baf,
                                                u16* __restrict__ bft) {
  __shared__ u16 t[64][65];
  int a0 = blockIdx.x * 64, d0 = blockIdx.y * 64, b = blockIdx.z;
  int tx = threadIdx.x & 63, ty = threadIdx.x >> 6;
  for (int r = ty; r < 64; r += 4) {
    int a = a0 + r;
    t[r][tx] = (a < AA) ? baf[((size_t)b * AA + a) * DD + d0 + tx] : (u16)0;
  }
  __syncthreads();
  for (int r = ty; r < 64; r += 4) {
    int a = a0 + tx;
    if (a < AA) bft[((size_t)b * DD + d0 + r) * KP + a] = t[tx][r];
  }
}

// ---------------- attn_w (1408,2783) f32 -> attw_t (2816,1408) bf16, zero pad ----------------
__global__ __launch_bounds__(256) void tr_attw_k(const float* __restrict__ w,
                                                 u16* __restrict__ wt) {
  __shared__ u16 t[64][65];
  int n0 = blockIdx.x * 64, k0 = blockIdx.y * 64;
  int tx = threadIdx.x & 63, ty = threadIdx.x >> 6;
  for (int r = ty; r < 64; r += 4) {
    int n = n0 + tx;
    t[r][tx] = (n < AM1) ? f2bf(w[(size_t)(k0 + r) * AM1 + n]) : (u16)0;
  }
  __syncthreads();
  for (int r = ty; r < 64; r += 4)
    wt[(size_t)(n0 + r) * 1408 + k0 + tx] = t[tx][r];
}

// ---------------- pack head weights: wt[n][k], n<2 cls, 2..145 reg, pad->160 ----------------
__global__ __launch_bounds__(256) void wt_k(const float* __restrict__ cw,
                                            const float* __restrict__ rw,
                                            u16* __restrict__ wt) {
  int n = blockIdx.x;
  for (int k = threadIdx.x; k < 2816; k += 256) {
    float v = 0.f;
    if (n < 2) v = cw[(size_t)k * 2 + n];
    else if (n < 146) v = rw[(size_t)k * 144 + (n - 2)];
    wt[(size_t)n * 2816 + k] = f2bf(v);
  }
}

// ---------------- props cols 2,3 = anchors[:,2:4] ----------------
__global__ __launch_bounds__(256) void anch_k(const float* __restrict__ anch,
                                              float* __restrict__ props) {
  int idx = blockIdx.x * 256 + threadIdx.x;
  if (idx >= MT) return;
  int a = idx % AA;
  props[(size_t)idx * 148 + 2] = anch[a * 148 + 2];
  props[(size_t)idx * 148 + 3] = anch[a * 148 + 3];
}

// ---------------- in-place row softmax on scattered bf16 attP rows (stride KP) ----------------
// WF32: additionally write normalized f32 row to fdst (stride AA) - fuses exp_k.
template <int WF32>
__global__ __launch_bounds__(256) void softmax_k(u16* __restrict__ attP,
                                                 float* __restrict__ fdst) {
  const int row = blockIdx.x;            // 0..MH-1
  const int i = row % AA;
  u16* p = attP + (size_t)row * KP;
  const int tid = threadIdx.x;
  const int c0 = tid, c1 = tid + 256;    // 352 chunks of 8 (incl. 4 pad chunks)
  const bool has1 = (c1 < 352);
  uint4 h0 = ((const uint4*)p)[c0];
  uint4 h1 = has1 ? ((const uint4*)p)[c1] : make_uint4(0, 0, 0, 0);
  float v0[8], v1[8];
  v0[0] = bf2f(h0.x & 0xffffu); v0[1] = bf2f(h0.x >> 16);
  v0[2] = bf2f(h0.y & 0xffffu); v0[3] = bf2f(h0.y >> 16);
  v0[4] = bf2f(h0.z & 0xffffu); v0[5] = bf2f(h0.z >> 16);
  v0[6] = bf2f(h0.w & 0xffffu); v0[7] = bf2f(h0.w >> 16);
  v1[0] = bf2f(h1.x & 0xffffu); v1[1] = bf2f(h1.x >> 16);
  v1[2] = bf2f(h1.y & 0xffffu); v1[3] = bf2f(h1.y >> 16);
  v1[4] = bf2f(h1.z & 0xffffu); v1[5] = bf2f(h1.z >> 16);
  v1[6] = bf2f(h1.w & 0xffffu); v1[7] = bf2f(h1.w >> 16);
  float mx = -3e38f;
#pragma unroll
  for (int e = 0; e < 8; ++e) { int j = c0 * 8 + e; if (j < AA && j != i) mx = fmaxf(mx, v0[e]); }
#pragma unroll
  for (int e = 0; e < 8; ++e) { int j = c1 * 8 + e; if (has1 && j < AA && j != i) mx = fmaxf(mx, v1[e]); }
#pragma unroll
  for (int o = 1; o < 64; o <<= 1) mx = fmaxf(mx, __shfl_xor(mx, o));
  __shared__ float rm[4], rs[4];
  if (!(tid & 63)) rm[tid >> 6] = mx;
  __syncthreads();
  mx = fmaxf(fmaxf(rm[0], rm[1]), fmaxf(rm[2], rm[3]));
  float s = 0.f, e0[8], e1[8];
#pragma unroll
  for (int e = 0; e < 8; ++e) {
    int j = c0 * 8 + e;
    float t = (j < AA && j != i) ? __expf(v0[e] - mx) : 0.f;
    e0[e] = t; s += t;
  }
#pragma unroll
  for (int e = 0; e < 8; ++e) {
    int j = c1 * 8 + e;
    float t = (has1 && j < AA && j != i) ? __expf(v1[e] - mx) : 0.f;
    e1[e] = t; s += t;
  }
#pragma unroll
  for (int o = 1; o < 64; o <<= 1) s += __shfl_xor(s, o);
  if (!(tid & 63)) rs[tid >> 6] = s;
  __syncthreads();
  s = (rs[0] + rs[1]) + (rs[2] + rs[3]);
  const float inv = 1.f / s;
#pragma unroll
  for (int e = 0; e < 8; ++e) e0[e] *= inv;
#pragma unroll
  for (int e = 0; e < 8; ++e) e1[e] *= inv;
  uint4 o0, o1;
  o0.x = (unsigned)f2bf(e0[0]) | ((unsigned)f2bf(e0[1]) << 16);
  o0.y = (unsigned)f2bf(e0[2]) | ((unsigned)f2bf(e0[3]) << 16);
  o0.z = (unsigned)f2bf(e0[4]) | ((unsigned)f2bf(e0[5]) << 16);
  o0.w = (unsigned)f2bf(e0[6]) | ((unsigned)f2bf(e0[7]) << 16);
  ((uint4*)p)[c0] = o0;
  if (has1) {
    o1.x = (unsigned)f2bf(e1[0]) | ((unsigned)f2bf(e1[1]) << 16);
    o1.y = (unsigned)f2bf(e1[2]) | ((unsigned)f2bf(e1[3]) << 16);
    o1.z = (unsigned)f2bf(e1[4]) | ((unsigned)f2bf(e1[5]) << 16);
    o1.w = (unsigned)f2bf(e1[6]) | ((unsigned)f2bf(e1[7]) << 16);
    ((uint4*)p)[c1] = o1;
  }
  if constexpr (WF32) {
    // 348 full chunks cover exactly AA=2784 cols; write bf16-rounded f32
    float4* dp = (float4*)(fdst + (size_t)row * AA);
    float4 f0, f1;
    f0.x = bf2f(o0.x & 0xffffu); f0.y = bf2f(o0.x >> 16);
    f0.z = bf2f(o0.y & 0xffffu); f0.w = bf2f(o0.y >> 16);
    f1.x = bf2f(o0.z & 0xffffu); f1.y = bf2f(o0.z >> 16);
    f1.z = bf2f(o0.w & 0xffffu); f1.w = bf2f(o0.w >> 16);
    dp[2 * c0] = f0; dp[2 * c0 + 1] = f1;
    if (c1 < 348) {
      float4 g0, g1;
      g0.x = bf2f(o1.x & 0xffffu); g0.y = bf2f(o1.x >> 16);
      g0.z = bf2f(o1.y & 0xffffu); g0.w = bf2f(o1.y >> 16);
      g1.x = bf2f(o1.z & 0xffffu); g1.y = bf2f(o1.z >> 16);
      g1.z = bf2f(o1.w & 0xffffu); g1.w = bf2f(o1.w >> 16);
      dp[2 * c1] = g0; dp[2 * c1 + 1] = g1;
    }
  }
}

// ---------------- bf16 (stride KP) -> f32 (stride AA) expand ----------------
__global__ __launch_bounds__(256) void exp_k(const u16* __restrict__ src,
                                             float* __restrict__ dst) {
  int row = blockIdx.y;
  int cc = blockIdx.x * 256 + threadIdx.x;
  if (cc >= 348) return;
  uint4 h = ((const uint4*)(src + (size_t)row * KP))[cc];
  float4 f0, f1;
  f0.x = bf2f(h.x & 0xffffu); f0.y = bf2f(h.x >> 16);
  f0.z = bf2f(h.y & 0xffffu); f0.w = bf2f(h.y >> 16);
  f1.x = bf2f(h.z & 0xffffu); f1.y = bf2f(h.z >> 16);
  f1.z = bf2f(h.w & 0xffffu); f1.w = bf2f(h.w >> 16);
  float4* dp = (float4*)(dst + (size_t)row * AA);
  dp[2 * cc] = f0;
  dp[2 * cc + 1] = f1;
}

// ---------------- head GEMM (2-phase, BN=160): [attf|baf] @ wt^T, fused epilogue ----------------
__global__ __launch_bounds__(256) void head_k(const u16* __restrict__ A1,
                                              const u16* __restrict__ A2,
                                              const u16* __restrict__ Bt,
                                              float* __restrict__ outf,
                                              const float* __restrict__ b1,
                                              const float* __restrict__ b2,
                                              const float* __restrict__ anch) {
  constexpr int K = 2816, NT = K / 32, BN = 160, HN = 80, NF = 5;
  __shared__ __align__(16) u16 As[2][128 * 32];
  __shared__ __align__(16) u16 Bs[2][BN * 32];
  const int tid = threadIdx.x;
  const int lane = tid & 63;
  const int wm = tid >> 7, wn = (tid >> 6) & 1;
  const int m0 = blockIdx.x * 128;
  const int l16 = lane & 15, lq = lane >> 4;

  auto stage = [&](int buf, int t) {
    const int k0 = t * 32;
    const u16* Asrc = (k0 < 1408) ? A1 : A2;
    const int kk = (k0 < 1408) ? k0 : k0 - 1408;
#pragma unroll
    for (int inst = 0; inst < 2; ++inst) {
      int c = tid + inst * 256;
      load16_lds(Asrc + (size_t)(m0 + (c >> 2)) * 1408 + kk + (c & 3) * 8, &As[buf][c * 8]);
    }
    for (int c = tid; c < BN * 4; c += 256)
      load16_lds(Bt + (size_t)(c >> 2) * K + k0 + (c & 3) * 8, &Bs[buf][c * 8]);
  };

  f32x4 acc[4][NF];
#pragma unroll
  for (int i = 0; i < 4; ++i)
#pragma unroll
    for (int j = 0; j < NF; ++j) acc[i][j] = 0.f;

  stage(0, 0);
  asm volatile("s_waitcnt vmcnt(0)" ::: "memory");
  __builtin_amdgcn_s_barrier();
  int cur = 0;
  for (int t = 0; t < NT; ++t) {
    if (t + 1 < NT) stage(cur ^ 1, t + 1);
    bf16x8 av[4], bv[NF];
#pragma unroll
    for (int mt = 0; mt < 4; ++mt)
      av[mt] = *(const bf16x8*)&As[cur][(wm * 64 + mt * 16 + l16) * 32 + lq * 8];
#pragma unroll
    for (int nt = 0; nt < NF; ++nt)
      bv[nt] = *(const bf16x8*)&Bs[cur][(wn * HN + nt * 16 + l16) * 32 + lq * 8];
#pragma unroll
    for (int mt = 0; mt < 4; ++mt)
#pragma unroll
      for (int nt = 0; nt < NF; ++nt)
        acc[mt][nt] = __builtin_amdgcn_mfma_f32_16x16x32_bf16(av[mt], bv[nt], acc[mt][nt], 0, 0, 0);
    asm volatile("s_waitcnt vmcnt(0)" ::: "memory");
    __builtin_amdgcn_s_barrier();
    cur ^= 1;
  }

#pragma unroll
  for (int nt = 0; nt < NF; ++nt) {
    int n = wn * HN + nt * 16 + l16;
    if (n >= 146) continue;
#pragma unroll
    for (int mt = 0; mt < 4; ++mt)
#pragma unroll
      for (int r = 0; r < 4; ++r) {
        int m = m0 + wm * 64 + mt * 16 + lq * 4 + r;
        int ii = m % AA;
        float v = acc[mt][nt][r];
        if (n < 2) {
          outf[(size_t)m * 148 + n] = v + b1[n];
        } else {
          int rr = n - 2;
          v += b2[rr];
          if (rr >= 72) v = 1.f / (1.f + __expf(-v));
          outf[(size_t)m * 148 + 4 + rr] = anch[ii * 148 + 4 + rr] + v;
        }
      }
  }
}

extern "C" void kernel_launch(void* const* d_in, const int* in_sizes, int n_in,
                              void* d_out, int out_size, void* d_ws, size_t ws_size,
                              hipStream_t stream) {
  const float* x       = (const float*)d_in[0];
  const float* conv_w  = (const float*)d_in[1];
  const float* conv_b  = (const float*)d_in[2];
  const float* attn_w  = (const float*)d_in[3];
  const float* attn_b  = (const float*)d_in[4];
  const float* cls_w   = (const float*)d_in[5];
  const float* cls_b   = (const float*)d_in[6];
  const float* reg_w   = (const float*)d_in[7];
  const float* reg_b   = (const float*)d_in[8];
  const float* anchors = (const float*)d_in[9];
  const int*   cut_xs  = (const int*)d_in[10];
  const unsigned char* inv = (const unsigned char*)d_in[11];

  float* props = (float*)d_out;
  float* attn  = props + (size_t)MT * 148;                   // f32 attn_mat out
  // park attf + feats + wt in the not-yet-written second half of attn
  // (written last by exp_k h=1, after all readers are done)
  u16* attf    = (u16*)((char*)attn + (size_t)MH * AA * 4);  // 62.7 MB
  char* park   = (char*)attf + (size_t)MT * DD * 2;
  float* feats = (float*)park;                               // 1.8 MB
  u16* wt      = (u16*)(park + 4 * 1024 * 1024);             // 0.9 MB

  // workspace carve-up (~197 MB, below the proven round-1/2 footprint)
  char* wp = (char*)d_ws;
  auto take = [&](size_t bytes) { char* p = wp; wp += (bytes + 255) & ~(size_t)255; return p; };
  u16* baf   = (u16*)take((size_t)MT * DD * 2);              // 62.7 MB
  u16* baft  = (u16*)take((size_t)NB * DD * KP * 2);         // 63.4 MB (stride KP)
  u16* attP  = (u16*)take((size_t)MH * KP * 2);              // 62.7 MB (4 batches, stride KP)
  u16* attwt = (u16*)take((size_t)KP * 1408 * 2);            // 7.9 MB

  conv_k<<<dim3(176), 256, 0, stream>>>(x, conv_w, conv_b, feats);
  gather_k<<<dim3(MT), 128, 0, stream>>>(feats, cut_xs, inv, baf);
  tr_baf_k<<<dim3(44, 22, 8), 256, 0, stream>>>(baf, baft);
  tr_attw_k<<<dim3(44, 22), 256, 0, stream>>>(attn_w, attwt);
  wt_k<<<dim3(160), 256, 0, stream>>>(cls_w, reg_w, wt);
  anch_k<<<dim3(87), 256, 0, stream>>>(anchors, props);

  for (int h = 0; h < 2; ++h) {
    // GEMM1: scores bf16, scattered (+bias) into attP (8-phase 256^2, T1 swizzle)
    gemm8_k<1><<<dim3(44, 11), 512, 0, stream>>>(
        baf + (size_t)h * MH * DD, attwt, attP, attn_b);
    // softmax in place on attP (diag -> 0, zero K-pad); h=0 also writes f32 attn
    if (h == 0)
      softmax_k<1><<<dim3(MH), 256, 0, stream>>>(attP, attn);
    else
      softmax_k<0><<<dim3(MH), 256, 0, stream>>>(attP, nullptr);
    // GEMM2: att_feat = attP @ baf^T, 4 batches via grid z (8-phase 256^2, T1 swizzle)
    gemm8_k<2><<<dim3(11, 6, 4), 512, 0, stream>>>(
        attP, baft + (size_t)h * 4 * DD * KP,
        attf + (size_t)h * 4 * AA * DD, nullptr);
  }
  // head GEMM: fused bias + sigmoid + anchors into props (reads attf)
  head_k<<<dim3(174), 256, 0, stream>>>(attf, baf, wt, props,
                                        cls_b, reg_b, anchors);
  // expand half-1 attn (clobbers attf/park region - safe, head_k done)
  exp_k<<<dim3(2, MH), 256, 0, stream>>>(attP, attn + (size_t)MH * AA);
}

// Round 5
// 834.308 us; speedup vs baseline: 1.6356x; 1.0680x over previous
//
#include <hip/hip_runtime.h>
#include <stdint.h>

typedef __attribute__((ext_vector_type(8))) __bf16 bf16x8;
typedef __attribute__((ext_vector_type(4))) float f32x4;
typedef unsigned short u16;

#define DEV static __device__ __forceinline__

constexpr int NB = 8;           // batch
constexpr int AA = 2784;        // anchors
constexpr int AM1 = 2783;       // A-1
constexpr int DD = 1408;        // D = 64*22
constexpr int MT = NB * AA;     // 22272 total rows
constexpr int MH = MT / 2;      // 11136 rows per half (4 batches)
constexpr int KP = 2816;        // padded K / attP row stride (mult of 64)

DEV u16 f2bf(float f) {
  uint32_t u = __builtin_bit_cast(uint32_t, f);
  u += 0x7FFFu + ((u >> 16) & 1u);
  return (u16)(u >> 16);
}
DEV float bf2f(unsigned v) { return __builtin_bit_cast(float, v << 16); }

// async global->LDS, 16B per lane. LDS dest is wave-uniform base + lane*16 by HW.
DEV void load16_lds(const void* g, void* l) {
  auto gp = (const __attribute__((address_space(1))) uint32_t*)(uintptr_t)g;
  auto lp = (__attribute__((address_space(3))) uint32_t*)(uint32_t)(uintptr_t)l;
  __builtin_amdgcn_global_load_lds(gp, lp, 16, 0, 0);
}

#define VMW(n) asm volatile("s_waitcnt vmcnt(" #n ")" ::: "memory")
#define LGW0 asm volatile("s_waitcnt lgkmcnt(0)" ::: "memory")
#define BARR asm volatile("s_barrier" ::: "memory")
#define SCHB __builtin_amdgcn_sched_barrier(0)

// 16 MFMAs of one quadrant (compile-time QM/QN keep acc indices static)
template <int QM, int QN>
DEV void mfma16(f32x4 (&acc)[8][4], const bf16x8 (&Av)[4][2], const bf16x8 (&Bv)[2][2]) {
  __builtin_amdgcn_s_setprio(1);
#pragma unroll
  for (int mt = 0; mt < 4; ++mt)
#pragma unroll
    for (int nt = 0; nt < 2; ++nt)
#pragma unroll
      for (int ks = 0; ks < 2; ++ks)
        acc[QM * 4 + mt][QN * 2 + nt] = __builtin_amdgcn_mfma_f32_16x16x32_bf16(
            Av[mt][ks], Bv[nt][ks], acc[QM * 4 + mt][QN * 2 + nt], 0, 0, 0);
  __builtin_amdgcn_s_setprio(0);
}

// ---------------- GEMM1: 256x256 8-phase, scores -> scattered bf16 into attP ----------------
__global__ __launch_bounds__(512) void gemm8_k(const u16* __restrict__ A,
                                               const u16* __restrict__ Bt,
                                               u16* __restrict__ outh,
                                               const float* __restrict__ b1) {
  constexpr int K = 1408, LDA = 1408, LDB = 1408;
  constexpr int MR = MH, NRB = KP;
  constexpr int NT2 = K / 128;
  __shared__ u16 As_[2][16384];
  __shared__ u16 Bs_[2][16384];
  const int tid = threadIdx.x;
  const int lane = tid & 63;
  const int w = tid >> 6;
  const int wr = w >> 2, wc = w & 3;
  const int l16 = lane & 15, lq = lane >> 4;

  // T1 bijective XCD swizzle, y-fastest within chunk
  const int gx = gridDim.x, gy = gridDim.y;
  const int nwg = gx * gy;
  const int i = blockIdx.x + blockIdx.y * gx;
  const int xcd = i & 7, pos = i >> 3;
  const int q = nwg >> 3, r = nwg & 7;
  const int lid = (xcd < r ? xcd * (q + 1) : r * (q + 1) + (xcd - r) * q) + pos;
  const int m0 = (lid / gy) * 256, n0 = (lid % gy) * 256;

  const u16* Ab = A;
  const u16* Bb = Bt;

  auto stA = [&](int buf, int half, int kt) {
#pragma unroll
    for (int inst = 0; inst < 2; ++inst) {
      int c = tid + inst * 512;
      int row = c >> 3, sl = c & 7;
      int sr = m0 + half * 128 + row;
      sr = sr < MR - 1 ? sr : MR - 1;
      load16_lds(Ab + (size_t)sr * LDA + kt * 64 + ((sl ^ (row & 7)) * 8),
                 &As_[buf][half * 8192 + c * 8]);
    }
  };
  auto stB = [&](int buf, int half, int kt) {
#pragma unroll
    for (int inst = 0; inst < 2; ++inst) {
      int c = tid + inst * 512;
      int row = c >> 3, sl = c & 7;
      int sr = n0 + half * 128 + row;
      sr = sr < NRB - 1 ? sr : NRB - 1;
      load16_lds(Bb + (size_t)sr * LDB + kt * 64 + ((sl ^ (row & 7)) * 8),
                 &Bs_[buf][half * 8192 + c * 8]);
    }
  };
  auto rdA = [&](int buf, int qm, bf16x8 (&a)[4][2]) {
#pragma unroll
    for (int mt = 0; mt < 4; ++mt)
#pragma unroll
      for (int ks = 0; ks < 2; ++ks) {
        int row = wr * 128 + qm * 64 + mt * 16 + l16;
        int ch = (ks * 4 + lq) ^ (row & 7);
        a[mt][ks] = *(const bf16x8*)&As_[buf][row * 64 + ch * 8];
      }
  };
  auto rdB = [&](int buf, int qn, bf16x8 (&b)[2][2]) {
#pragma unroll
    for (int nt = 0; nt < 2; ++nt)
#pragma unroll
      for (int ks = 0; ks < 2; ++ks) {
        int row = wc * 64 + qn * 32 + nt * 16 + l16;
        int ch = (ks * 4 + lq) ^ (row & 7);
        b[nt][ks] = *(const bf16x8*)&Bs_[buf][row * 64 + ch * 8];
      }
  };

  f32x4 acc[8][4];
#pragma unroll
  for (int i2 = 0; i2 < 8; ++i2)
#pragma unroll
    for (int j = 0; j < 4; ++j) acc[i2][j] = 0.f;

  bf16x8 aL[4][2], aH[4][2], bL[2][2], bH[2][2];

  stA(0, 0, 0); stA(0, 1, 0); stB(0, 0, 0); stB(0, 1, 0);
  stA(1, 0, 1); stB(1, 0, 1); stB(1, 1, 1);
  VMW(6);
  BARR;

  for (int t = 0; t < NT2; ++t) {
    const int kt0 = 2 * t, kt1 = 2 * t + 1;
    const bool tail = (t == NT2 - 1);
    rdA(0, 0, aL); rdB(0, 0, bL);
    stA(1, 1, kt1);
    BARR; LGW0; SCHB;
    mfma16<0, 0>(acc, aL, bL);
    BARR;
    rdB(0, 1, bH);
    if (!tail) stA(0, 0, kt0 + 2);
    BARR; LGW0; SCHB;
    mfma16<0, 1>(acc, aL, bH);
    BARR;
    rdA(0, 1, aH);
    if (!tail) stB(0, 0, kt0 + 2);
    BARR; LGW0; SCHB;
    mfma16<1, 0>(acc, aH, bL);
    BARR;
    if (!tail) { stB(0, 1, kt0 + 2); VMW(6); } else { VMW(0); }
    BARR; SCHB;
    mfma16<1, 1>(acc, aH, bH);
    BARR;
    rdA(1, 0, aL); rdB(1, 0, bL);
    if (!tail) stA(0, 1, kt0 + 2);
    BARR; LGW0; SCHB;
    mfma16<0, 0>(acc, aL, bL);
    BARR;
    rdB(1, 1, bH);
    if (!tail) stA(1, 0, kt1 + 2);
    BARR; LGW0; SCHB;
    mfma16<0, 1>(acc, aL, bH);
    BARR;
    rdA(1, 1, aH);
    if (!tail) stB(1, 0, kt1 + 2);
    BARR; LGW0; SCHB;
    mfma16<1, 0>(acc, aH, bL);
    BARR;
    if (!tail) { stB(1, 1, kt1 + 2); VMW(6); }
    BARR; SCHB;
    mfma16<1, 1>(acc, aH, bH);
    BARR;
  }

  // epilogue: scatter (+bias), skip diagonal.  C/D map: col=lane&15, row=(lane>>4)*4+reg
#pragma unroll
  for (int mi = 0; mi < 8; ++mi)
#pragma unroll
    for (int r2 = 0; r2 < 4; ++r2) {
      int m = m0 + wr * 128 + mi * 16 + lq * 4 + r2;
      if (m >= MR) continue;
      int ii = m % AA;
#pragma unroll
      for (int ni = 0; ni < 4; ++ni) {
        int n = n0 + wc * 64 + ni * 16 + l16;
        if (n >= AM1) continue;
        int col = n + (n >= ii);
        outh[(size_t)m * KP + col] = f2bf(acc[mi][ni][r2] + b1[n]);
      }
    }
}

// 16 MFMAs for the 256x128 kernel (acc[8][2])
template <int QM>
DEV void mfma16b(f32x4 (&acc)[8][2], const bf16x8 (&Av)[4][2], const bf16x8 (&Bv)[2][2]) {
  __builtin_amdgcn_s_setprio(1);
#pragma unroll
  for (int mt = 0; mt < 4; ++mt)
#pragma unroll
    for (int nt = 0; nt < 2; ++nt)
#pragma unroll
      for (int ks = 0; ks < 2; ++ks)
        acc[QM * 4 + mt][nt] = __builtin_amdgcn_mfma_f32_16x16x32_bf16(
            Av[mt][ks], Bv[nt][ks], acc[QM * 4 + mt][nt], 0, 0, 0);
  __builtin_amdgcn_s_setprio(0);
}

// ---------------- GEMM2: 256x128 4-phase: att_feat = attP @ baft^T (per batch z) ----------------
__global__ __launch_bounds__(512) void gemm2_k(const u16* __restrict__ A,
                                               const u16* __restrict__ Bt,
                                               u16* __restrict__ outh) {
  constexpr int K = KP;                 // 2816
  constexpr int NT2 = K / 128;          // 22 iterations, 2 K-tiles each
  __shared__ u16 As_[2][16384];         // 256 x 64
  __shared__ u16 Bs_[2][8192];          // 128 x 64
  const int tid = threadIdx.x;
  const int lane = tid & 63;
  const int w = tid >> 6;
  const int wr = w >> 2, wc = w & 3;    // 2 x 4 wave grid; wave tile 128x32
  const int l16 = lane & 15, lq = lane >> 4;

  const int gx = gridDim.x, gy = gridDim.y;
  const int nwg = gx * gy;              // 121
  const int i = blockIdx.x + blockIdx.y * gx;
  const int xcd = i & 7, pos = i >> 3;
  const int q = nwg >> 3, r = nwg & 7;
  const int lid = (xcd < r ? xcd * (q + 1) : r * (q + 1) + (xcd - r) * q) + pos;
  const int m0 = (lid / gy) * 256, n0 = (lid % gy) * 128;

  const int bz = blockIdx.z;
  const u16* Ab = A + (size_t)bz * AA * KP;
  const u16* Bb = Bt + (size_t)bz * DD * KP;
  u16* outp = outh + (size_t)bz * AA * DD;

  auto stA = [&](int buf, int half, int kt) {
#pragma unroll
    for (int inst = 0; inst < 2; ++inst) {
      int c = tid + inst * 512;
      int row = c >> 3, sl = c & 7;
      int sr = m0 + half * 128 + row;
      sr = sr < AA - 1 ? sr : AA - 1;
      load16_lds(Ab + (size_t)sr * KP + kt * 64 + ((sl ^ (row & 7)) * 8),
                 &As_[buf][half * 8192 + c * 8]);
    }
  };
  auto stB = [&](int buf, int kt) {
#pragma unroll
    for (int inst = 0; inst < 2; ++inst) {
      int c = tid + inst * 512;
      int row = c >> 3, sl = c & 7;
      int sr = n0 + row;                 // max 1407, in range
      load16_lds(Bb + (size_t)sr * KP + kt * 64 + ((sl ^ (row & 7)) * 8),
                 &Bs_[buf][c * 8]);
    }
  };
  auto rdA = [&](int buf, int qm, bf16x8 (&a)[4][2]) {
#pragma unroll
    for (int mt = 0; mt < 4; ++mt)
#pragma unroll
      for (int ks = 0; ks < 2; ++ks) {
        int row = wr * 128 + qm * 64 + mt * 16 + l16;
        int ch = (ks * 4 + lq) ^ (row & 7);
        a[mt][ks] = *(const bf16x8*)&As_[buf][row * 64 + ch * 8];
      }
  };
  auto rdB = [&](int buf, bf16x8 (&b)[2][2]) {
#pragma unroll
    for (int nt = 0; nt < 2; ++nt)
#pragma unroll
      for (int ks = 0; ks < 2; ++ks) {
        int row = wc * 32 + nt * 16 + l16;
        int ch = (ks * 4 + lq) ^ (row & 7);
        b[nt][ks] = *(const bf16x8*)&Bs_[buf][row * 64 + ch * 8];
      }
  };

  f32x4 acc[8][2];
#pragma unroll
  for (int i2 = 0; i2 < 8; ++i2)
#pragma unroll
    for (int j = 0; j < 2; ++j) acc[i2][j] = 0.f;

  bf16x8 aL[4][2], aH[4][2], bb[2][2];

  // prologue: b0{Alo,Ahi,B}(kt0), b1{Alo,B}(kt1) -> 10 insts; wait b0 (leave 4)
  stA(0, 0, 0); stA(0, 1, 0); stB(0, 0);
  stA(1, 0, 1); stB(1, 1);
  VMW(4);
  BARR;

  for (int t = 0; t < NT2; ++t) {
    const int kt0 = 2 * t, kt1 = 2 * t + 1;
    const bool tail = (t == NT2 - 1);
    // P0: read b0{Alo,B}; stage b1.Ahi(kt1)
    rdA(0, 0, aL); rdB(0, bb);
    stA(1, 1, kt1);
    BARR; LGW0; SCHB;
    mfma16b<0>(acc, aL, bb);
    BARR;
    // P1: read b0.Ahi; stage b0.Alo(kt0+2); counted wait -> b1 complete
    rdA(0, 1, aH);
    if (!tail) { stA(0, 0, kt0 + 2); VMW(2); } else { VMW(0); }
    BARR; LGW0; SCHB;
    mfma16b<1>(acc, aH, bb);
    BARR;
    // P2: read b1{Alo,B}; stage b0.Ahi(kt0+2)
    rdA(1, 0, aL); rdB(1, bb);
    if (!tail) stA(0, 1, kt0 + 2);
    BARR; LGW0; SCHB;
    mfma16b<0>(acc, aL, bb);
    BARR;
    // P3: read b1.Ahi; stage b0.B(kt0+2) + b1{Alo,B}(kt1+2); wait b0-next (leave 4)
    rdA(1, 1, aH);
    if (!tail) { stB(0, kt0 + 2); stA(1, 0, kt1 + 2); stB(1, kt1 + 2); VMW(4); }
    BARR; LGW0; SCHB;
    mfma16b<1>(acc, aH, bb);
    BARR;
  }

  // epilogue: n always < 1408
#pragma unroll
  for (int mi = 0; mi < 8; ++mi)
#pragma unroll
    for (int r2 = 0; r2 < 4; ++r2) {
      int m = m0 + wr * 128 + mi * 16 + lq * 4 + r2;
      if (m >= AA) continue;
      size_t base = (size_t)m * DD;
#pragma unroll
      for (int ni = 0; ni < 2; ++ni) {
        int n = n0 + wc * 32 + ni * 16 + l16;
        outp[base + n] = f2bf(acc[mi][ni][r2]);
      }
    }
}

// ---------------- 1x1 conv: feats[b][o][h][w] ----------------
__global__ __launch_bounds__(256) void conv_k(const float* __restrict__ x,
                                              const float* __restrict__ w,
                                              const float* __restrict__ bias,
                                              float* __restrict__ feats) {
  __shared__ float xs[256 * 40];
  int bb = blockIdx.x / 22, h = blockIdx.x % 22;
  const float* xp = x + (size_t)bb * 256 * 880 + h * 40;
  for (int l = threadIdx.x; l < 256 * 40; l += 256)
    xs[l] = xp[(l / 40) * 880 + (l % 40)];
  __syncthreads();
  for (int l = threadIdx.x; l < 64 * 40; l += 256) {
    int o = l / 40, ww = l % 40;
    float acc = bias[o];
    const float* wr = w + o * 256;
#pragma unroll 8
    for (int c = 0; c < 256; ++c) acc += xs[c * 40 + ww] * wr[c];
    feats[((size_t)(bb * 64 + o) * 22 + h) * 40 + ww] = acc;
  }
}

// ---------------- fused gather + mask -> baf (B,A,D) AND baf_t (B,D,A+pad) ----------------
__global__ __launch_bounds__(256) void gt_k(const float* __restrict__ feats,
                                            const int* __restrict__ cut,
                                            const unsigned char* __restrict__ inv,
                                            u16* __restrict__ baf,
                                            u16* __restrict__ bft) {
  unsigned probe = 0;
#pragma unroll
  for (int t = 0; t < 10; ++t)
    probe |= (unsigned)inv[4 * t + 1] | (unsigned)inv[4 * t + 2] | (unsigned)inv[4 * t + 3];
  const bool is_u8 = (probe != 0);  // i32 storage -> high bytes all zero
  __shared__ u16 t[64][65];
  int a0 = blockIdx.x * 64, d0 = blockIdx.y * 64, b = blockIdx.z;
  int tx = threadIdx.x & 63, ty = threadIdx.x >> 6;
  int d = d0 + tx, o = d / 22, h = d - o * 22;
  for (int r = ty; r < 64; r += 4) {
    int a = a0 + r;
    u16 hv = 0;
    if (a < AA) {
      int msk = is_u8 ? (int)inv[a * 22 + h] : ((const int*)inv)[a * 22 + h];
      float v = 0.f;
      if (!msk) v = feats[((size_t)(b * 64 + o) * 22 + h) * 40 + cut[a * 22 + h]];
      hv = f2bf(v);
      baf[((size_t)b * AA + a) * DD + d] = hv;
    }
    t[r][tx] = hv;
  }
  __syncthreads();
  for (int r = ty; r < 64; r += 4) {
    int a = a0 + tx;
    if (a < AA) bft[((size_t)b * DD + d0 + r) * KP + a] = t[tx][r];
  }
}

// ---------------- attn_w (1408,2783) f32 -> attw_t (2816,1408) bf16, zero pad ----------------
__global__ __launch_bounds__(256) void tr_attw_k(const float* __restrict__ w,
                                                 u16* __restrict__ wt) {
  __shared__ u16 t[64][65];
  int n0 = blockIdx.x * 64, k0 = blockIdx.y * 64;
  int tx = threadIdx.x & 63, ty = threadIdx.x >> 6;
  for (int r = ty; r < 64; r += 4) {
    int n = n0 + tx;
    t[r][tx] = (n < AM1) ? f2bf(w[(size_t)(k0 + r) * AM1 + n]) : (u16)0;
  }
  __syncthreads();
  for (int r = ty; r < 64; r += 4)
    wt[(size_t)(n0 + r) * 1408 + k0 + tx] = t[tx][r];
}

// ---------------- pack head weights: wt[n][k], n<2 cls, 2..145 reg, pad->160 ----------------
__global__ __launch_bounds__(256) void wt_k(const float* __restrict__ cw,
                                            const float* __restrict__ rw,
                                            u16* __restrict__ wt) {
  int n = blockIdx.x;
  for (int k = threadIdx.x; k < 2816; k += 256) {
    float v = 0.f;
    if (n < 2) v = cw[(size_t)k * 2 + n];
    else if (n < 146) v = rw[(size_t)k * 144 + (n - 2)];
    wt[(size_t)n * 2816 + k] = f2bf(v);
  }
}

// ---------------- in-place row softmax on scattered bf16 attP rows (stride KP) ----------------
// WF32: additionally write normalized f32 row to fdst (stride AA) - fuses exp_k.
template <int WF32>
__global__ __launch_bounds__(256) void softmax_k(u16* __restrict__ attP,
                                                 float* __restrict__ fdst) {
  const int row = blockIdx.x;            // 0..MH-1
  const int i = row % AA;
  u16* p = attP + (size_t)row * KP;
  const int tid = threadIdx.x;
  const int c0 = tid, c1 = tid + 256;    // 352 chunks of 8 (incl. 4 pad chunks)
  const bool has1 = (c1 < 352);
  uint4 h0 = ((const uint4*)p)[c0];
  uint4 h1 = has1 ? ((const uint4*)p)[c1] : make_uint4(0, 0, 0, 0);
  float v0[8], v1[8];
  v0[0] = bf2f(h0.x & 0xffffu); v0[1] = bf2f(h0.x >> 16);
  v0[2] = bf2f(h0.y & 0xffffu); v0[3] = bf2f(h0.y >> 16);
  v0[4] = bf2f(h0.z & 0xffffu); v0[5] = bf2f(h0.z >> 16);
  v0[6] = bf2f(h0.w & 0xffffu); v0[7] = bf2f(h0.w >> 16);
  v1[0] = bf2f(h1.x & 0xffffu); v1[1] = bf2f(h1.x >> 16);
  v1[2] = bf2f(h1.y & 0xffffu); v1[3] = bf2f(h1.y >> 16);
  v1[4] = bf2f(h1.z & 0xffffu); v1[5] = bf2f(h1.z >> 16);
  v1[6] = bf2f(h1.w & 0xffffu); v1[7] = bf2f(h1.w >> 16);
  float mx = -3e38f;
#pragma unroll
  for (int e = 0; e < 8; ++e) { int j = c0 * 8 + e; if (j < AA && j != i) mx = fmaxf(mx, v0[e]); }
#pragma unroll
  for (int e = 0; e < 8; ++e) { int j = c1 * 8 + e; if (has1 && j < AA && j != i) mx = fmaxf(mx, v1[e]); }
#pragma unroll
  for (int o = 1; o < 64; o <<= 1) mx = fmaxf(mx, __shfl_xor(mx, o));
  __shared__ float rm[4], rs[4];
  if (!(tid & 63)) rm[tid >> 6] = mx;
  __syncthreads();
  mx = fmaxf(fmaxf(rm[0], rm[1]), fmaxf(rm[2], rm[3]));
  float s = 0.f, e0[8], e1[8];
#pragma unroll
  for (int e = 0; e < 8; ++e) {
    int j = c0 * 8 + e;
    float t = (j < AA && j != i) ? __expf(v0[e] - mx) : 0.f;
    e0[e] = t; s += t;
  }
#pragma unroll
  for (int e = 0; e < 8; ++e) {
    int j = c1 * 8 + e;
    float t = (has1 && j < AA && j != i) ? __expf(v1[e] - mx) : 0.f;
    e1[e] = t; s += t;
  }
#pragma unroll
  for (int o = 1; o < 64; o <<= 1) s += __shfl_xor(s, o);
  if (!(tid & 63)) rs[tid >> 6] = s;
  __syncthreads();
  s = (rs[0] + rs[1]) + (rs[2] + rs[3]);
  const float inv = 1.f / s;
#pragma unroll
  for (int e = 0; e < 8; ++e) e0[e] *= inv;
#pragma unroll
  for (int e = 0; e < 8; ++e) e1[e] *= inv;
  uint4 o0, o1;
  o0.x = (unsigned)f2bf(e0[0]) | ((unsigned)f2bf(e0[1]) << 16);
  o0.y = (unsigned)f2bf(e0[2]) | ((unsigned)f2bf(e0[3]) << 16);
  o0.z = (unsigned)f2bf(e0[4]) | ((unsigned)f2bf(e0[5]) << 16);
  o0.w = (unsigned)f2bf(e0[6]) | ((unsigned)f2bf(e0[7]) << 16);
  ((uint4*)p)[c0] = o0;
  if (has1) {
    o1.x = (unsigned)f2bf(e1[0]) | ((unsigned)f2bf(e1[1]) << 16);
    o1.y = (unsigned)f2bf(e1[2]) | ((unsigned)f2bf(e1[3]) << 16);
    o1.z = (unsigned)f2bf(e1[4]) | ((unsigned)f2bf(e1[5]) << 16);
    o1.w = (unsigned)f2bf(e1[6]) | ((unsigned)f2bf(e1[7]) << 16);
    ((uint4*)p)[c1] = o1;
  }
  if constexpr (WF32) {
    float4* dp = (float4*)(fdst + (size_t)row * AA);
    float4 f0, f1;
    f0.x = bf2f(o0.x & 0xffffu); f0.y = bf2f(o0.x >> 16);
    f0.z = bf2f(o0.y & 0xffffu); f0.w = bf2f(o0.y >> 16);
    f1.x = bf2f(o0.z & 0xffffu); f1.y = bf2f(o0.z >> 16);
    f1.z = bf2f(o0.w & 0xffffu); f1.w = bf2f(o0.w >> 16);
    dp[2 * c0] = f0; dp[2 * c0 + 1] = f1;
    if (c1 < 348) {
      float4 g0, g1;
      g0.x = bf2f(o1.x & 0xffffu); g0.y = bf2f(o1.x >> 16);
      g0.z = bf2f(o1.y & 0xffffu); g0.w = bf2f(o1.y >> 16);
      g1.x = bf2f(o1.z & 0xffffu); g1.y = bf2f(o1.z >> 16);
      g1.z = bf2f(o1.w & 0xffffu); g1.w = bf2f(o1.w >> 16);
      dp[2 * c1] = g0; dp[2 * c1 + 1] = g1;
    }
  }
}

// ---------------- bf16 (stride KP) -> f32 (stride AA) expand ----------------
__global__ __launch_bounds__(256) void exp_k(const u16* __restrict__ src,
                                             float* __restrict__ dst) {
  int row = blockIdx.y;
  int cc = blockIdx.x * 256 + threadIdx.x;
  if (cc >= 348) return;
  uint4 h = ((const uint4*)(src + (size_t)row * KP))[cc];
  float4 f0, f1;
  f0.x = bf2f(h.x & 0xffffu); f0.y = bf2f(h.x >> 16);
  f0.z = bf2f(h.y & 0xffffu); f0.w = bf2f(h.y >> 16);
  f1.x = bf2f(h.z & 0xffffu); f1.y = bf2f(h.z >> 16);
  f1.z = bf2f(h.w & 0xffffu); f1.w = bf2f(h.w >> 16);
  float4* dp = (float4*)(dst + (size_t)row * AA);
  dp[2 * cc] = f0;
  dp[2 * cc + 1] = f1;
}

// ---------------- head GEMM (2-phase, BN=160): [attf|baf] @ wt^T, fused epilogue + anchors ----------------
__global__ __launch_bounds__(256) void head_k(const u16* __restrict__ A1,
                                              const u16* __restrict__ A2,
                                              const u16* __restrict__ Bt,
                                              float* __restrict__ outf,
                                              const float* __restrict__ b1,
                                              const float* __restrict__ b2,
                                              const float* __restrict__ anch) {
  constexpr int K = 2816, NT = K / 32, BN = 160, HN = 80, NF = 5;
  __shared__ __align__(16) u16 As[2][128 * 32];
  __shared__ __align__(16) u16 Bs[2][BN * 32];
  const int tid = threadIdx.x;
  const int lane = tid & 63;
  const int wm = tid >> 7, wn = (tid >> 6) & 1;
  const int m0 = blockIdx.x * 128;
  const int l16 = lane & 15, lq = lane >> 4;

  auto stage = [&](int buf, int t) {
    const int k0 = t * 32;
    const u16* Asrc = (k0 < 1408) ? A1 : A2;
    const int kk = (k0 < 1408) ? k0 : k0 - 1408;
#pragma unroll
    for (int inst = 0; inst < 2; ++inst) {
      int c = tid + inst * 256;
      load16_lds(Asrc + (size_t)(m0 + (c >> 2)) * 1408 + kk + (c & 3) * 8, &As[buf][c * 8]);
    }
    for (int c = tid; c < BN * 4; c += 256)
      load16_lds(Bt + (size_t)(c >> 2) * K + k0 + (c & 3) * 8, &Bs[buf][c * 8]);
  };

  f32x4 acc[4][NF];
#pragma unroll
  for (int i = 0; i < 4; ++i)
#pragma unroll
    for (int j = 0; j < NF; ++j) acc[i][j] = 0.f;

  stage(0, 0);
  asm volatile("s_waitcnt vmcnt(0)" ::: "memory");
  __builtin_amdgcn_s_barrier();
  int cur = 0;
  for (int t = 0; t < NT; ++t) {
    if (t + 1 < NT) stage(cur ^ 1, t + 1);
    bf16x8 av[4], bv[NF];
#pragma unroll
    for (int mt = 0; mt < 4; ++mt)
      av[mt] = *(const bf16x8*)&As[cur][(wm * 64 + mt * 16 + l16) * 32 + lq * 8];
#pragma unroll
    for (int nt = 0; nt < NF; ++nt)
      bv[nt] = *(const bf16x8*)&Bs[cur][(wn * HN + nt * 16 + l16) * 32 + lq * 8];
#pragma unroll
    for (int mt = 0; mt < 4; ++mt)
#pragma unroll
      for (int nt = 0; nt < NF; ++nt)
        acc[mt][nt] = __builtin_amdgcn_mfma_f32_16x16x32_bf16(av[mt], bv[nt], acc[mt][nt], 0, 0, 0);
    asm volatile("s_waitcnt vmcnt(0)" ::: "memory");
    __builtin_amdgcn_s_barrier();
    cur ^= 1;
  }

#pragma unroll
  for (int nt = 0; nt < NF; ++nt) {
    int n = wn * HN + nt * 16 + l16;
    if (n >= 146) continue;
#pragma unroll
    for (int mt = 0; mt < 4; ++mt)
#pragma unroll
      for (int r = 0; r < 4; ++r) {
        int m = m0 + wm * 64 + mt * 16 + lq * 4 + r;
        int ii = m % AA;
        float v = acc[mt][nt][r];
        if (n < 2) {
          outf[(size_t)m * 148 + n] = v + b1[n];
          if (n == 0) {
            outf[(size_t)m * 148 + 2] = anch[ii * 148 + 2];
            outf[(size_t)m * 148 + 3] = anch[ii * 148 + 3];
          }
        } else {
          int rr = n - 2;
          v += b2[rr];
          if (rr >= 72) v = 1.f / (1.f + __expf(-v));
          outf[(size_t)m * 148 + 4 + rr] = anch[ii * 148 + 4 + rr] + v;
        }
      }
  }
}

extern "C" void kernel_launch(void* const* d_in, const int* in_sizes, int n_in,
                              void* d_out, int out_size, void* d_ws, size_t ws_size,
                              hipStream_t stream) {
  const float* x       = (const float*)d_in[0];
  const float* conv_w  = (const float*)d_in[1];
  const float* conv_b  = (const float*)d_in[2];
  const float* attn_w  = (const float*)d_in[3];
  const float* attn_b  = (const float*)d_in[4];
  const float* cls_w   = (const float*)d_in[5];
  const float* cls_b   = (const float*)d_in[6];
  const float* reg_w   = (const float*)d_in[7];
  const float* reg_b   = (const float*)d_in[8];
  const float* anchors = (const float*)d_in[9];
  const int*   cut_xs  = (const int*)d_in[10];
  const unsigned char* inv = (const unsigned char*)d_in[11];

  float* props = (float*)d_out;
  float* attn  = props + (size_t)MT * 148;                   // f32 attn_mat out
  // park attf + feats + wt in the not-yet-written second half of attn
  // (written last by exp_k h=1, after all readers are done)
  u16* attf    = (u16*)((char*)attn + (size_t)MH * AA * 4);  // 62.7 MB
  char* park   = (char*)attf + (size_t)MT * DD * 2;
  float* feats = (float*)park;                               // 1.8 MB
  u16* wt      = (u16*)(park + 4 * 1024 * 1024);             // 0.9 MB

  // workspace carve-up (~197 MB, proven footprint)
  char* wp = (char*)d_ws;
  auto take = [&](size_t bytes) { char* p = wp; wp += (bytes + 255) & ~(size_t)255; return p; };
  u16* baf   = (u16*)take((size_t)MT * DD * 2);              // 62.7 MB
  u16* baft  = (u16*)take((size_t)NB * DD * KP * 2);         // 63.4 MB (stride KP)
  u16* attP  = (u16*)take((size_t)MH * KP * 2);              // 62.7 MB (4 batches, stride KP)
  u16* attwt = (u16*)take((size_t)KP * 1408 * 2);            // 7.9 MB

  conv_k<<<dim3(176), 256, 0, stream>>>(x, conv_w, conv_b, feats);
  gt_k<<<dim3(44, 22, 8), 256, 0, stream>>>(feats, cut_xs, inv, baf, baft);
  tr_attw_k<<<dim3(44, 22), 256, 0, stream>>>(attn_w, attwt);
  wt_k<<<dim3(160), 256, 0, stream>>>(cls_w, reg_w, wt);

  for (int h = 0; h < 2; ++h) {
    // GEMM1: scores bf16, scattered (+bias) into attP (8-phase 256^2, T1 swizzle)
    gemm8_k<<<dim3(44, 11), 512, 0, stream>>>(
        baf + (size_t)h * MH * DD, attwt, attP, attn_b);
    // softmax in place on attP (diag -> 0, zero K-pad); h=0 also writes f32 attn
    if (h == 0)
      softmax_k<1><<<dim3(MH), 256, 0, stream>>>(attP, attn);
    else
      softmax_k<0><<<dim3(MH), 256, 0, stream>>>(attP, nullptr);
    // GEMM2: att_feat = attP @ baf^T, 256x128 4-phase, 4 batches via grid z
    gemm2_k<<<dim3(11, 11, 4), 512, 0, stream>>>(
        attP, baft + (size_t)h * 4 * DD * KP,
        attf + (size_t)h * 4 * AA * DD);
  }
  // head GEMM: fused bias + sigmoid + anchors (incl. cols 2,3) into props
  head_k<<<dim3(174), 256, 0, stream>>>(attf, baf, wt, props,
                                        cls_b, reg_b, anchors);
  // expand half-1 attn (clobbers attf/park region - safe, head_k done)
  exp_k<<<dim3(2, MH), 256, 0, stream>>>(attP, attn + (size_t)MH * AA);
}

// Round 6
// 777.855 us; speedup vs baseline: 1.7543x; 1.0726x over previous
//
#include <hip/hip_runtime.h>
#include <stdint.h>

typedef __attribute__((ext_vector_type(8))) __bf16 bf16x8;
typedef __attribute__((ext_vector_type(4))) float f32x4;
typedef unsigned short u16;
typedef unsigned char u8;

#define DEV static __device__ __forceinline__

constexpr int NB = 8;           // batch
constexpr int AA = 2784;        // anchors
constexpr int AM1 = 2783;       // A-1
constexpr int DD = 1408;        // D = 64*22
constexpr int MT = NB * AA;     // 22272 total rows
constexpr int MH = MT / 2;      // 11136 rows per half (4 batches)
constexpr int KP = 2816;        // padded K / attP row stride (mult of 128)

DEV u16 f2bf(float f) {
  uint32_t u = __builtin_bit_cast(uint32_t, f);
  u += 0x7FFFu + ((u >> 16) & 1u);
  return (u16)(u >> 16);
}
DEV float bf2f(unsigned v) { return __builtin_bit_cast(float, v << 16); }
DEV u8 f2f8(float f) {
  return (u8)(__builtin_amdgcn_cvt_pk_fp8_f32(f, f, 0, false) & 0xff);
}
DEV float4 cv4(unsigned w) {
  float4 r;
  r.x = __builtin_amdgcn_cvt_f32_fp8((int)w, 0);
  r.y = __builtin_amdgcn_cvt_f32_fp8((int)w, 1);
  r.z = __builtin_amdgcn_cvt_f32_fp8((int)w, 2);
  r.w = __builtin_amdgcn_cvt_f32_fp8((int)w, 3);
  return r;
}
DEV unsigned pk4(float a, float b, float c, float d) {
  int r = __builtin_amdgcn_cvt_pk_fp8_f32(a, b, 0, false);
  r = __builtin_amdgcn_cvt_pk_fp8_f32(c, d, r, true);
  return (unsigned)r;
}

// async global->LDS, 16B per lane. LDS dest is wave-uniform base + lane*16 by HW.
DEV void load16_lds(const void* g, void* l) {
  auto gp = (const __attribute__((address_space(1))) uint32_t*)(uintptr_t)g;
  auto lp = (__attribute__((address_space(3))) uint32_t*)(uint32_t)(uintptr_t)l;
  __builtin_amdgcn_global_load_lds(gp, lp, 16, 0, 0);
}

#define VMW0 asm volatile("s_waitcnt vmcnt(0)" ::: "memory")
#define LGW0 asm volatile("s_waitcnt lgkmcnt(0)" ::: "memory")
#define BARR asm volatile("s_barrier" ::: "memory")
#define SCHB __builtin_amdgcn_sched_barrier(0)

// 16 fp8 MFMAs of one quadrant (acc[8][4] kernel)
template <int QM, int QN>
DEV void mf16a(f32x4 (&acc)[8][4], const long (&Av)[4][2], const long (&Bv)[2][2]) {
  __builtin_amdgcn_s_setprio(1);
#pragma unroll
  for (int mt = 0; mt < 4; ++mt)
#pragma unroll
    for (int nt = 0; nt < 2; ++nt)
#pragma unroll
      for (int ks = 0; ks < 2; ++ks)
        acc[QM * 4 + mt][QN * 2 + nt] = __builtin_amdgcn_mfma_f32_16x16x32_fp8_fp8(
            Av[mt][ks], Bv[nt][ks], acc[QM * 4 + mt][QN * 2 + nt], 0, 0, 0);
  __builtin_amdgcn_s_setprio(0);
}
// 16 fp8 MFMAs for acc[8][2] kernel
template <int QM>
DEV void mf16b(f32x4 (&acc)[8][2], const long (&Av)[4][2], const long (&Bv)[2][2]) {
  __builtin_amdgcn_s_setprio(1);
#pragma unroll
  for (int mt = 0; mt < 4; ++mt)
#pragma unroll
    for (int nt = 0; nt < 2; ++nt)
#pragma unroll
      for (int ks = 0; ks < 2; ++ks)
        acc[QM * 4 + mt][nt] = __builtin_amdgcn_mfma_f32_16x16x32_fp8_fp8(
            Av[mt][ks], Bv[nt][ks], acc[QM * 4 + mt][nt], 0, 0, 0);
  __builtin_amdgcn_s_setprio(0);
}

// ---------------- GEMM1 fp8: 256x256 8-phase, K=1408. scores -> scattered fp8 attP ----------------
__global__ __launch_bounds__(512) void gemm1_k(const u8* __restrict__ A,
                                               const u8* __restrict__ Bt,
                                               u8* __restrict__ outh,
                                               const float* __restrict__ b1) {
  constexpr int MR = MH;
  constexpr int NT = 11;                 // 1408 / 128
  __shared__ __align__(16) u8 As8[2][32768];
  __shared__ __align__(16) u8 Bs8[2][32768];
  const int tid = threadIdx.x;
  const int lane = tid & 63;
  const int w = tid >> 6;
  const int wr = w >> 2, wc = w & 3;
  const int l16 = lane & 15, lq = lane >> 4;
  const int l7 = l16 & 7, lqh = lq >> 1, lql = lq & 1;

  // T1 bijective XCD swizzle, y-fastest within chunk
  const int gx = gridDim.x, gy = gridDim.y;
  const int nwg = gx * gy;
  const int i = blockIdx.x + blockIdx.y * gx;
  const int xcd = i & 7, pos = i >> 3;
  const int q = nwg >> 3, r = nwg & 7;
  const int lid = (xcd < r ? xcd * (q + 1) : r * (q + 1) + (xcd - r) * q) + pos;
  const int m0 = (lid / gy) * 256, n0 = (lid % gy) * 256;

  auto stA = [&](int buf, int half, int kt) {
#pragma unroll
    for (int inst = 0; inst < 2; ++inst) {
      int c = tid + inst * 512;
      int row = c >> 3, sl = c & 7;
      int sr = m0 + half * 128 + row;
      sr = sr < MR - 1 ? sr : MR - 1;
      load16_lds(A + (size_t)sr * 1408 + kt * 128 + ((sl ^ (row & 7)) << 4),
                 &As8[buf][half * 16384 + (c << 4)]);
    }
  };
  auto stB = [&](int buf, int half, int kt) {
#pragma unroll
    for (int inst = 0; inst < 2; ++inst) {
      int c = tid + inst * 512;
      int row = c >> 3, sl = c & 7;
      int sr = n0 + half * 128 + row;     // <= 2815, always valid (padded)
      load16_lds(Bt + (size_t)sr * 1408 + kt * 128 + ((sl ^ (row & 7)) << 4),
                 &Bs8[buf][half * 16384 + (c << 4)]);
    }
  };
  auto rdA = [&](int buf, int qm, int kh, long (&a)[4][2]) {
#pragma unroll
    for (int mt = 0; mt < 4; ++mt)
#pragma unroll
      for (int ks = 0; ks < 2; ++ks) {
        int rloc = qm * 64 + mt * 16 + l16;
        int slot = (kh * 4 + ks * 2 + lqh) ^ l7;
        a[mt][ks] = *(const long*)&As8[buf][wr * 16384 + rloc * 128 + slot * 16 + lql * 8];
      }
  };
  auto rdB = [&](int buf, int qn, int kh, long (&b)[2][2]) {
#pragma unroll
    for (int nt = 0; nt < 2; ++nt)
#pragma unroll
      for (int ks = 0; ks < 2; ++ks) {
        int R = wc * 64 + qn * 32 + nt * 16 + l16;
        int slot = (kh * 4 + ks * 2 + lqh) ^ l7;
        b[nt][ks] = *(const long*)&Bs8[buf][(R >> 7) * 16384 + (R & 127) * 128 + slot * 16 + lql * 8];
      }
  };

  f32x4 acc[8][4];
#pragma unroll
  for (int i2 = 0; i2 < 8; ++i2)
#pragma unroll
    for (int j = 0; j < 4; ++j) acc[i2][j] = 0.f;

  long aL[4][2], aH[4][2], bL[2][2], bH[2][2];

  stA(0, 0, 0); stA(0, 1, 0); stB(0, 0, 0); stB(0, 1, 0);
  VMW0; BARR;
  int cur = 0;
  for (int t = 0; t < NT; ++t) {
    const bool tail = (t == NT - 1);
    const int nxt = cur ^ 1;
    // P0
    rdA(cur, 0, 0, aL); rdB(cur, 0, 0, bL);
    if (!tail) stA(nxt, 0, t + 1);
    BARR; LGW0; SCHB; mf16a<0, 0>(acc, aL, bL); BARR;
    // P1
    rdB(cur, 1, 0, bH);
    if (!tail) stA(nxt, 1, t + 1);
    BARR; LGW0; SCHB; mf16a<0, 1>(acc, aL, bH); BARR;
    // P2
    rdA(cur, 1, 0, aH);
    if (!tail) stB(nxt, 0, t + 1);
    BARR; LGW0; SCHB; mf16a<1, 0>(acc, aH, bL); BARR;
    // P3
    if (!tail) stB(nxt, 1, t + 1);
    BARR; SCHB; mf16a<1, 1>(acc, aH, bH); BARR;
    // P4
    rdA(cur, 0, 1, aL); rdB(cur, 0, 1, bL);
    BARR; LGW0; SCHB; mf16a<0, 0>(acc, aL, bL); BARR;
    // P5
    rdB(cur, 1, 1, bH);
    BARR; LGW0; SCHB; mf16a<0, 1>(acc, aL, bH); BARR;
    // P6
    rdA(cur, 1, 1, aH);
    BARR; LGW0; SCHB; mf16a<1, 0>(acc, aH, bL); BARR;
    // P7: drain staging (aged >= 4 phases), then finish
    VMW0;
    BARR; SCHB; mf16a<1, 1>(acc, aH, bH); BARR;
    cur = nxt;
  }

  // epilogue: scatter fp8 (+bias), skip diagonal. C/D map: col=lane&15, row=(lane>>4)*4+reg
#pragma unroll
  for (int mi = 0; mi < 8; ++mi)
#pragma unroll
    for (int r2 = 0; r2 < 4; ++r2) {
      int m = m0 + wr * 128 + mi * 16 + lq * 4 + r2;
      if (m >= MR) continue;
      int ii = m % AA;
#pragma unroll
      for (int ni = 0; ni < 4; ++ni) {
        int n = n0 + wc * 64 + ni * 16 + l16;
        if (n >= AM1) continue;
        int col = n + (n >= ii);
        outh[(size_t)m * KP + col] = f2f8(acc[mi][ni][r2] + b1[n]);
      }
    }
}

// ---------------- GEMM2 fp8: 256x128 4-phase, K=2816. att_feat = attP @ baft^T ----------------
__global__ __launch_bounds__(512) void gemm2_k(const u8* __restrict__ A,
                                               const u8* __restrict__ Bt,
                                               u16* __restrict__ outh) {
  constexpr int NT = 22;                 // 2816 / 128
  __shared__ __align__(16) u8 As8[2][32768];
  __shared__ __align__(16) u8 Bs8[2][16384];
  const int tid = threadIdx.x;
  const int lane = tid & 63;
  const int w = tid >> 6;
  const int wr = w >> 2, wc = w & 3;     // wave tile 128 x 32
  const int l16 = lane & 15, lq = lane >> 4;
  const int l7 = l16 & 7, lqh = lq >> 1, lql = lq & 1;

  const int gx = gridDim.x, gy = gridDim.y;
  const int nwg = gx * gy;               // 121
  const int i = blockIdx.x + blockIdx.y * gx;
  const int xcd = i & 7, pos = i >> 3;
  const int q = nwg >> 3, r = nwg & 7;
  const int lid = (xcd < r ? xcd * (q + 1) : r * (q + 1) + (xcd - r) * q) + pos;
  const int m0 = (lid / gy) * 256, n0 = (lid % gy) * 128;

  const int bz = blockIdx.z;
  const u8* Ab = A + (size_t)bz * AA * KP;
  const u8* Bb = Bt + (size_t)bz * DD * KP;
  u16* outp = outh + (size_t)bz * AA * DD;

  auto stA = [&](int buf, int half, int kt) {
#pragma unroll
    for (int inst = 0; inst < 2; ++inst) {
      int c = tid + inst * 512;
      int row = c >> 3, sl = c & 7;
      int sr = m0 + half * 128 + row;
      sr = sr < AA - 1 ? sr : AA - 1;
      load16_lds(Ab + (size_t)sr * KP + kt * 128 + ((sl ^ (row & 7)) << 4),
                 &As8[buf][half * 16384 + (c << 4)]);
    }
  };
  auto stB = [&](int buf, int kt) {
#pragma unroll
    for (int inst = 0; inst < 2; ++inst) {
      int c = tid + inst * 512;
      int row = c >> 3, sl = c & 7;
      int sr = n0 + row;                  // <= 1407
      load16_lds(Bb + (size_t)sr * KP + kt * 128 + ((sl ^ (row & 7)) << 4),
                 &Bs8[buf][c << 4]);
    }
  };
  auto rdA = [&](int buf, int qm, int kh, long (&a)[4][2]) {
#pragma unroll
    for (int mt = 0; mt < 4; ++mt)
#pragma unroll
      for (int ks = 0; ks < 2; ++ks) {
        int rloc = qm * 64 + mt * 16 + l16;
        int slot = (kh * 4 + ks * 2 + lqh) ^ l7;
        a[mt][ks] = *(const long*)&As8[buf][wr * 16384 + rloc * 128 + slot * 16 + lql * 8];
      }
  };
  auto rdB = [&](int buf, int kh, long (&b)[2][2]) {
#pragma unroll
    for (int nt = 0; nt < 2; ++nt)
#pragma unroll
      for (int ks = 0; ks < 2; ++ks) {
        int R = wc * 32 + nt * 16 + l16;  // 0..127
        int slot = (kh * 4 + ks * 2 + lqh) ^ l7;
        b[nt][ks] = *(const long*)&Bs8[buf][R * 128 + slot * 16 + lql * 8];
      }
  };

  f32x4 acc[8][2];
#pragma unroll
  for (int i2 = 0; i2 < 8; ++i2)
#pragma unroll
    for (int j = 0; j < 2; ++j) acc[i2][j] = 0.f;

  long aL[4][2], aH[4][2], bb[2][2];

  stA(0, 0, 0); stA(0, 1, 0); stB(0, 0);
  VMW0; BARR;
  int cur = 0;
  for (int t = 0; t < NT; ++t) {
    const bool tail = (t == NT - 1);
    const int nxt = cur ^ 1;
    // P0
    rdA(cur, 0, 0, aL); rdB(cur, 0, bb);
    if (!tail) stA(nxt, 0, t + 1);
    BARR; LGW0; SCHB; mf16b<0>(acc, aL, bb); BARR;
    // P1
    rdA(cur, 1, 0, aH);
    if (!tail) stA(nxt, 1, t + 1);
    BARR; LGW0; SCHB; mf16b<1>(acc, aH, bb); BARR;
    // P2
    rdA(cur, 0, 1, aL); rdB(cur, 1, bb);
    if (!tail) stB(nxt, t + 1);
    BARR; LGW0; SCHB; mf16b<0>(acc, aL, bb); BARR;
    // P3: finish, then drain staging before buffer switch
    rdA(cur, 1, 1, aH);
    BARR; LGW0; SCHB; mf16b<1>(acc, aH, bb);
    VMW0; BARR;
    cur = nxt;
  }

  // epilogue: acc holds 256 * att_feat (attP scaled by 256)
#pragma unroll
  for (int mi = 0; mi < 8; ++mi)
#pragma unroll
    for (int r2 = 0; r2 < 4; ++r2) {
      int m = m0 + wr * 128 + mi * 16 + lq * 4 + r2;
      if (m >= AA) continue;
      size_t base = (size_t)m * DD;
#pragma unroll
      for (int nt = 0; nt < 2; ++nt) {
        int n = n0 + wc * 32 + nt * 16 + l16;
        outp[base + n] = f2bf(acc[mi][nt][r2] * 0.00390625f);
      }
    }
}

// ---------------- 1x1 conv: feats[b][o][h][w] ----------------
__global__ __launch_bounds__(256) void conv_k(const float* __restrict__ x,
                                              const float* __restrict__ w,
                                              const float* __restrict__ bias,
                                              float* __restrict__ feats) {
  __shared__ float xs[256 * 40];
  int bb = blockIdx.x / 22, h = blockIdx.x % 22;
  const float* xp = x + (size_t)bb * 256 * 880 + h * 40;
  for (int l = threadIdx.x; l < 256 * 40; l += 256)
    xs[l] = xp[(l / 40) * 880 + (l % 40)];
  __syncthreads();
  for (int l = threadIdx.x; l < 64 * 40; l += 256) {
    int o = l / 40, ww = l % 40;
    float acc = bias[o];
    const float* wr = w + o * 256;
#pragma unroll 8
    for (int c = 0; c < 256; ++c) acc += xs[c * 40 + ww] * wr[c];
    feats[((size_t)(bb * 64 + o) * 22 + h) * 40 + ww] = acc;
  }
}

// ---------------- fused gather+mask -> baf bf16, baf8 fp8, baft8 fp8^T ----------------
__global__ __launch_bounds__(256) void gt_k(const float* __restrict__ feats,
                                            const int* __restrict__ cut,
                                            const u8* __restrict__ inv,
                                            u16* __restrict__ baf,
                                            u8* __restrict__ baf8,
                                            u8* __restrict__ bft8) {
  unsigned probe = 0;
#pragma unroll
  for (int t = 0; t < 10; ++t)
    probe |= (unsigned)inv[4 * t + 1] | (unsigned)inv[4 * t + 2] | (unsigned)inv[4 * t + 3];
  const bool is_u8 = (probe != 0);  // i32 storage -> high bytes all zero
  __shared__ u8 t8[64][65];
  int a0 = blockIdx.x * 64, d0 = blockIdx.y * 64, b = blockIdx.z;
  int tx = threadIdx.x & 63, ty = threadIdx.x >> 6;
  int d = d0 + tx, o = d / 22, h = d - o * 22;
  for (int r = ty; r < 64; r += 4) {
    int a = a0 + r;
    u8 f8 = 0;
    if (a < AA) {
      int msk = is_u8 ? (int)inv[a * 22 + h] : ((const int*)inv)[a * 22 + h];
      float v = 0.f;
      if (!msk) v = feats[((size_t)(b * 64 + o) * 22 + h) * 40 + cut[a * 22 + h]];
      baf[((size_t)b * AA + a) * DD + d] = f2bf(v);
      f8 = f2f8(v);
      baf8[((size_t)b * AA + a) * DD + d] = f8;
    }
    t8[r][tx] = f8;
  }
  __syncthreads();
  for (int r = ty; r < 64; r += 4) {
    int a = a0 + tx;
    if (a < AA) bft8[((size_t)b * DD + d0 + r) * KP + a] = t8[tx][r];
  }
}

// ---------------- attn_w (1408,2783) f32 -> attwt8 (2816,1408) fp8, zero pad ----------------
__global__ __launch_bounds__(256) void tr_attw_k(const float* __restrict__ w,
                                                 u8* __restrict__ wt8) {
  __shared__ u8 t8[64][65];
  int n0 = blockIdx.x * 64, k0 = blockIdx.y * 64;
  int tx = threadIdx.x & 63, ty = threadIdx.x >> 6;
  for (int r = ty; r < 64; r += 4) {
    int n = n0 + tx;
    t8[r][tx] = (n < AM1) ? f2f8(w[(size_t)(k0 + r) * AM1 + n]) : (u8)0;
  }
  __syncthreads();
  for (int r = ty; r < 64; r += 4)
    wt8[(size_t)(n0 + r) * 1408 + k0 + tx] = t8[tx][r];
}

// ---------------- pack head weights bf16: wt[n][k], n<2 cls, 2..145 reg, pad->160 ----------------
__global__ __launch_bounds__(256) void wt_k(const float* __restrict__ cw,
                                            const float* __restrict__ rw,
                                            u16* __restrict__ wt) {
  int n = blockIdx.x;
  for (int k = threadIdx.x; k < 2816; k += 256) {
    float v = 0.f;
    if (n < 2) v = cw[(size_t)k * 2 + n];
    else if (n < 146) v = rw[(size_t)k * 144 + (n - 2)];
    wt[(size_t)n * 2816 + k] = f2bf(v);
  }
}

// ---------------- fp8 row softmax in place (stride KP bytes); out = attn*256 fp8 ----------------
// WF32: also write normalized f32 row to fdst (stride AA)
template <int WF32>
__global__ __launch_bounds__(256) void softf_k(u8* __restrict__ attP,
                                               float* __restrict__ fdst) {
  const int row = blockIdx.x;            // 0..MH-1
  const int i = row % AA;
  u8* p = attP + (size_t)row * KP;
  const int t = threadIdx.x;
  const bool act = (t < 176);            // 176 uint4 chunks of 16 fp8
  uint4 qw = act ? ((const uint4*)p)[t] : make_uint4(0, 0, 0, 0);
  float v[16];
  { float4 f = cv4(qw.x); v[0] = f.x; v[1] = f.y; v[2] = f.z; v[3] = f.w; }
  { float4 f = cv4(qw.y); v[4] = f.x; v[5] = f.y; v[6] = f.z; v[7] = f.w; }
  { float4 f = cv4(qw.z); v[8] = f.x; v[9] = f.y; v[10] = f.z; v[11] = f.w; }
  { float4 f = cv4(qw.w); v[12] = f.x; v[13] = f.y; v[14] = f.z; v[15] = f.w; }
  const int base = t * 16;
  float mx = -3e38f;
#pragma unroll
  for (int e = 0; e < 16; ++e) {
    int j = base + e;
    if (act && j < AA && j != i) mx = fmaxf(mx, v[e]);
  }
#pragma unroll
  for (int o = 1; o < 64; o <<= 1) mx = fmaxf(mx, __shfl_xor(mx, o));
  __shared__ float rm[4], rs[4];
  if (!(t & 63)) rm[t >> 6] = mx;
  __syncthreads();
  mx = fmaxf(fmaxf(rm[0], rm[1]), fmaxf(rm[2], rm[3]));
  float s = 0.f, ev[16];
#pragma unroll
  for (int e = 0; e < 16; ++e) {
    int j = base + e;
    float tv = (act && j < AA && j != i) ? __expf(v[e] - mx) : 0.f;
    ev[e] = tv; s += tv;
  }
#pragma unroll
  for (int o = 1; o < 64; o <<= 1) s += __shfl_xor(s, o);
  if (!(t & 63)) rs[t >> 6] = s;
  __syncthreads();
  s = (rs[0] + rs[1]) + (rs[2] + rs[3]);
  const float inv = 1.f / s;
#pragma unroll
  for (int e = 0; e < 16; ++e) ev[e] *= inv;
  if (act) {
    const float sc = 256.f;
    uint4 ow;
    ow.x = pk4(ev[0] * sc, ev[1] * sc, ev[2] * sc, ev[3] * sc);
    ow.y = pk4(ev[4] * sc, ev[5] * sc, ev[6] * sc, ev[7] * sc);
    ow.z = pk4(ev[8] * sc, ev[9] * sc, ev[10] * sc, ev[11] * sc);
    ow.w = pk4(ev[12] * sc, ev[13] * sc, ev[14] * sc, ev[15] * sc);
    ((uint4*)p)[t] = ow;
    if (WF32 && t < 174) {
      float4* dp = (float4*)(fdst + (size_t)row * AA + base);
      dp[0] = make_float4(ev[0], ev[1], ev[2], ev[3]);
      dp[1] = make_float4(ev[4], ev[5], ev[6], ev[7]);
      dp[2] = make_float4(ev[8], ev[9], ev[10], ev[11]);
      dp[3] = make_float4(ev[12], ev[13], ev[14], ev[15]);
    }
  }
}

// ---------------- fp8*256 (stride KP) -> f32 (stride AA) expand ----------------
__global__ __launch_bounds__(256) void exp_k(const u8* __restrict__ src,
                                             float* __restrict__ dst) {
  int row = blockIdx.x;
  int t = threadIdx.x;
  if (t >= 174) return;
  uint4 qw = ((const uint4*)(src + (size_t)row * KP))[t];
  const float is = 0.00390625f;
  float4 f0 = cv4(qw.x), f1 = cv4(qw.y), f2 = cv4(qw.z), f3 = cv4(qw.w);
  float4* dp = (float4*)(dst + (size_t)row * AA + t * 16);
  dp[0] = make_float4(f0.x * is, f0.y * is, f0.z * is, f0.w * is);
  dp[1] = make_float4(f1.x * is, f1.y * is, f1.z * is, f1.w * is);
  dp[2] = make_float4(f2.x * is, f2.y * is, f2.z * is, f2.w * is);
  dp[3] = make_float4(f3.x * is, f3.y * is, f3.z * is, f3.w * is);
}

// ---------------- head GEMM (bf16, 2-phase, BN=160): [attf|baf] @ wt^T, fused epilogue ----------------
__global__ __launch_bounds__(256) void head_k(const u16* __restrict__ A1,
                                              const u16* __restrict__ A2,
                                              const u16* __restrict__ Bt,
                                              float* __restrict__ outf,
                                              const float* __restrict__ b1,
                                              const float* __restrict__ b2,
                                              const float* __restrict__ anch) {
  constexpr int K = 2816, NT = K / 32, BN = 160, HN = 80, NF = 5;
  __shared__ __align__(16) u16 As[2][128 * 32];
  __shared__ __align__(16) u16 Bs[2][BN * 32];
  const int tid = threadIdx.x;
  const int lane = tid & 63;
  const int wm = tid >> 7, wn = (tid >> 6) & 1;
  const int m0 = blockIdx.x * 128;
  const int l16 = lane & 15, lq = lane >> 4;

  auto stage = [&](int buf, int t) {
    const int k0 = t * 32;
    const u16* Asrc = (k0 < 1408) ? A1 : A2;
    const int kk = (k0 < 1408) ? k0 : k0 - 1408;
#pragma unroll
    for (int inst = 0; inst < 2; ++inst) {
      int c = tid + inst * 256;
      load16_lds(Asrc + (size_t)(m0 + (c >> 2)) * 1408 + kk + (c & 3) * 8, &As[buf][c * 8]);
    }
    for (int c = tid; c < BN * 4; c += 256)
      load16_lds(Bt + (size_t)(c >> 2) * K + k0 + (c & 3) * 8, &Bs[buf][c * 8]);
  };

  f32x4 acc[4][NF];
#pragma unroll
  for (int i = 0; i < 4; ++i)
#pragma unroll
    for (int j = 0; j < NF; ++j) acc[i][j] = 0.f;

  stage(0, 0);
  VMW0;
  __builtin_amdgcn_s_barrier();
  int cur = 0;
  for (int t = 0; t < NT; ++t) {
    if (t + 1 < NT) stage(cur ^ 1, t + 1);
    bf16x8 av[4], bv[NF];
#pragma unroll
    for (int mt = 0; mt < 4; ++mt)
      av[mt] = *(const bf16x8*)&As[cur][(wm * 64 + mt * 16 + l16) * 32 + lq * 8];
#pragma unroll
    for (int nt = 0; nt < NF; ++nt)
      bv[nt] = *(const bf16x8*)&Bs[cur][(wn * HN + nt * 16 + l16) * 32 + lq * 8];
#pragma unroll
    for (int mt = 0; mt < 4; ++mt)
#pragma unroll
      for (int nt = 0; nt < NF; ++nt)
        acc[mt][nt] = __builtin_amdgcn_mfma_f32_16x16x32_bf16(av[mt], bv[nt], acc[mt][nt], 0, 0, 0);
    VMW0;
    __builtin_amdgcn_s_barrier();
    cur ^= 1;
  }

#pragma unroll
  for (int nt = 0; nt < NF; ++nt) {
    int n = wn * HN + nt * 16 + l16;
    if (n >= 146) continue;
#pragma unroll
    for (int mt = 0; mt < 4; ++mt)
#pragma unroll
      for (int r = 0; r < 4; ++r) {
        int m = m0 + wm * 64 + mt * 16 + lq * 4 + r;
        int ii = m % AA;
        float v = acc[mt][nt][r];
        if (n < 2) {
          outf[(size_t)m * 148 + n] = v + b1[n];
          if (n == 0) {
            outf[(size_t)m * 148 + 2] = anch[ii * 148 + 2];
            outf[(size_t)m * 148 + 3] = anch[ii * 148 + 3];
          }
        } else {
          int rr = n - 2;
          v += b2[rr];
          if (rr >= 72) v = 1.f / (1.f + __expf(-v));
          outf[(size_t)m * 148 + 4 + rr] = anch[ii * 148 + 4 + rr] + v;
        }
      }
  }
}

extern "C" void kernel_launch(void* const* d_in, const int* in_sizes, int n_in,
                              void* d_out, int out_size, void* d_ws, size_t ws_size,
                              hipStream_t stream) {
  const float* x       = (const float*)d_in[0];
  const float* conv_w  = (const float*)d_in[1];
  const float* conv_b  = (const float*)d_in[2];
  const float* attn_w  = (const float*)d_in[3];
  const float* attn_b  = (const float*)d_in[4];
  const float* cls_w   = (const float*)d_in[5];
  const float* cls_b   = (const float*)d_in[6];
  const float* reg_w   = (const float*)d_in[7];
  const float* reg_b   = (const float*)d_in[8];
  const float* anchors = (const float*)d_in[9];
  const int*   cut_xs  = (const int*)d_in[10];
  const u8*    inv     = (const u8*)d_in[11];

  float* props = (float*)d_out;
  float* attn  = props + (size_t)MT * 148;                   // f32 attn_mat out
  // park attf + feats + wt in the not-yet-written second half of attn
  u16* attf    = (u16*)((char*)attn + (size_t)MH * AA * 4);  // 62.7 MB
  char* park   = (char*)attf + (size_t)MT * DD * 2;
  float* feats = (float*)park;                               // 1.8 MB
  u16* wt      = (u16*)(park + 4 * 1024 * 1024);             // 0.9 MB

  // workspace carve-up (~161 MB, below proven footprint)
  char* wp = (char*)d_ws;
  auto take = [&](size_t bytes) { char* p = wp; wp += (bytes + 255) & ~(size_t)255; return p; };
  u16* baf    = (u16*)take((size_t)MT * DD * 2);             // 62.7 MB bf16 (head)
  u8*  baf8   = (u8*)take((size_t)MT * DD);                  // 31.4 MB fp8 (GEMM1 A)
  u8*  baft8  = (u8*)take((size_t)NB * DD * KP);             // 31.7 MB fp8^T (GEMM2 B)
  u8*  attP8  = (u8*)take((size_t)MH * KP);                  // 31.4 MB fp8 scores/attn
  u8*  attwt8 = (u8*)take((size_t)KP * 1408);                // 4.0 MB fp8 (GEMM1 B)

  conv_k<<<dim3(176), 256, 0, stream>>>(x, conv_w, conv_b, feats);
  gt_k<<<dim3(44, 22, 8), 256, 0, stream>>>(feats, cut_xs, inv, baf, baf8, baft8);
  tr_attw_k<<<dim3(44, 22), 256, 0, stream>>>(attn_w, attwt8);
  wt_k<<<dim3(160), 256, 0, stream>>>(cls_w, reg_w, wt);

  for (int h = 0; h < 2; ++h) {
    // GEMM1: fp8 scores scattered (+bias) into attP8
    gemm1_k<<<dim3(44, 11), 512, 0, stream>>>(
        baf8 + (size_t)h * MH * DD, attwt8, attP8, attn_b);
    // softmax in place (diag/pad -> 0); h=0 also writes f32 attn
    if (h == 0)
      softf_k<1><<<dim3(MH), 256, 0, stream>>>(attP8, attn);
    else
      softf_k<0><<<dim3(MH), 256, 0, stream>>>(attP8, nullptr);
    // GEMM2: att_feat = attP8 @ baft8^T (x256 scale folded out in epilogue)
    gemm2_k<<<dim3(11, 11, 4), 512, 0, stream>>>(
        attP8, baft8 + (size_t)h * 4 * DD * KP,
        attf + (size_t)h * 4 * AA * DD);
  }
  // head GEMM (bf16): fused bias + sigmoid + anchors into props
  head_k<<<dim3(174), 256, 0, stream>>>(attf, baf, wt, props,
                                        cls_b, reg_b, anchors);
  // expand half-1 attn from fp8 (clobber-safe: head_k done)
  exp_k<<<dim3(MH), 256, 0, stream>>>(attP8, attn + (size_t)MH * AA);
}